// Round 23
// baseline (714.293 us; speedup 1.0000x reference)
//
#include <hip/hip_runtime.h>
#include <cstddef>
#include <cstdint>
#include <cmath>

// Problem constants
constexpr int BB = 4, TT = 2048, DD = 768, HH = 8, HD = 96, FF = 2048, LL = 2;
constexpr int MM = BB * TT;              // 8192
constexpr size_t HROW = (size_t)MM * DD; // 6291456
constexpr int CH = 64;                   // scan chunk length
constexpr int NCH = TT / CH;             // 32 chunks per sequence
constexpr int RP = 100;                  // padded LDS row (floats)
constexpr int KP = 104;                  // padded LDS row (ushorts)

typedef float f32x4 __attribute__((ext_vector_type(4)));
typedef short bf16x8 __attribute__((ext_vector_type(8)));
typedef unsigned short u16x8 __attribute__((ext_vector_type(8)));

__device__ __forceinline__ void gload16(const void* g, void* l) {
    __builtin_amdgcn_global_load_lds(
        (const __attribute__((address_space(1))) void*)g,
        (__attribute__((address_space(3))) void*)l, 16, 0, 0);
}
__device__ __forceinline__ float bf2f(unsigned short u) {
    return __uint_as_float(((unsigned)u) << 16);
}
__device__ __forceinline__ unsigned short f2bf(float f) {
    unsigned u = __float_as_uint(f);
    unsigned r = (u + 0x7fffu + ((u >> 16) & 1u)) >> 16;
    return (unsigned short)r;
}
__device__ __forceinline__ float silu_f(float v) {
    return v / (1.f + __expf(-v));
}
// XCD-aware bijective swizzle of linear workgroup id (nwg % 8 == 0)
__device__ __forceinline__ int xcd_swz(int wg, int nwg) {
    return (wg & 7) * (nwg >> 3) + (wg >> 3);
}

// ---------------------------------------------------------------- LayerNorm (f32 in) -> bf16
__global__ __launch_bounds__(256)
void layernorm_rows(const float* __restrict__ x, unsigned short* __restrict__ y,
                    const float* __restrict__ w, const float* __restrict__ b,
                    const float* mask)
{
    const int row = blockIdx.x;
    const int tid = threadIdx.x;
    const float* xr = x + (size_t)row * DD;
    float v0 = xr[tid], v1 = xr[tid + 256], v2 = xr[tid + 512];
    float s = v0 + v1 + v2;
    float ss = v0 * v0 + v1 * v1 + v2 * v2;
#pragma unroll
    for (int i = 1; i < 64; i <<= 1) { s += __shfl_xor(s, i); ss += __shfl_xor(ss, i); }
    __shared__ float red[8];
    const int wid = tid >> 6, lane = tid & 63;
    if (lane == 0) { red[wid] = s; red[4 + wid] = ss; }
    __syncthreads();
    const float S  = red[0] + red[1] + red[2] + red[3];
    const float SS = red[4] + red[5] + red[6] + red[7];
    const float mean = S * (1.f / DD);
    const float var  = SS * (1.f / DD) - mean * mean;
    const float rstd = rsqrtf(var + 1e-5f);
    const float m = mask ? mask[row] : 1.f;
    unsigned short* yr = y + (size_t)row * DD;
    yr[tid]       = f2bf(((v0 - mean) * rstd * w[tid]       + b[tid])       * m);
    yr[tid + 256] = f2bf(((v1 - mean) * rstd * w[tid + 256] + b[tid + 256]) * m);
    yr[tid + 512] = f2bf(((v2 - mean) * rstd * w[tid + 512] + b[tid + 512]) * m);
}

// ---------------------------------------------------------------- LayerNorm (bf16 in) -> bf16
__global__ __launch_bounds__(256)
void layernorm_rows_b(const unsigned short* __restrict__ x, unsigned short* __restrict__ y,
                      const float* __restrict__ w, const float* __restrict__ b,
                      const float* mask)
{
    const int row = blockIdx.x;
    const int tid = threadIdx.x;
    const unsigned short* xr = x + (size_t)row * DD;
    float v0 = bf2f(xr[tid]), v1 = bf2f(xr[tid + 256]), v2 = bf2f(xr[tid + 512]);
    float s = v0 + v1 + v2;
    float ss = v0 * v0 + v1 * v1 + v2 * v2;
#pragma unroll
    for (int i = 1; i < 64; i <<= 1) { s += __shfl_xor(s, i); ss += __shfl_xor(ss, i); }
    __shared__ float red[8];
    const int wid = tid >> 6, lane = tid & 63;
    if (lane == 0) { red[wid] = s; red[4 + wid] = ss; }
    __syncthreads();
    const float S  = red[0] + red[1] + red[2] + red[3];
    const float SS = red[4] + red[5] + red[6] + red[7];
    const float mean = S * (1.f / DD);
    const float var  = SS * (1.f / DD) - mean * mean;
    const float rstd = rsqrtf(var + 1e-5f);
    const float m = mask ? mask[row] : 1.f;
    unsigned short* yr = y + (size_t)row * DD;
    yr[tid]       = f2bf(((v0 - mean) * rstd * w[tid]       + b[tid])       * m);
    yr[tid + 256] = f2bf(((v1 - mean) * rstd * w[tid + 256] + b[tid + 256]) * m);
    yr[tid + 512] = f2bf(((v2 - mean) * rstd * w[tid + 512] + b[tid + 512]) * m);
}

// ---------------------------------------------------------------- batched transpose+convert
__global__ __launch_bounds__(256)
void transcvt_all(const float* __restrict__ proj,
                  const float* __restrict__ Wq, const float* __restrict__ Wk,
                  const float* __restrict__ Wv, const float* __restrict__ Wo,
                  const float* __restrict__ Wfb, const float* __restrict__ Wgb,
                  const float* __restrict__ Wfa, const float* __restrict__ Wga,
                  const float* __restrict__ Wb, const float* __restrict__ Wgate,
                  const float* __restrict__ Wup, const float* __restrict__ Wdown,
                  unsigned short* __restrict__ wt)
{
    const int bid = blockIdx.x;
    const float* in; unsigned short* out; int K, N, sub;
    if (bid < 576) { in = proj; out = wt; K = 768; N = 768; sub = bid; }
    else {
        const int rem = bid - 576;
        const int l = rem / 7392, r = rem - l * 7392;
        unsigned short* wl = wt + 589824 + (size_t)l * 7421952;
        if (r < 2304) {
            const int j = r / 576; sub = r % 576;
            in = (j == 0 ? Wq : j == 1 ? Wk : j == 2 ? Wv : Wo) + (size_t)l * 589824;
            out = (j < 3) ? (wl + (size_t)j * 589824) : (wl + 1966080);
            K = 768; N = 768;
        } else if (r < 2448) {
            const int j = (r - 2304) / 72; sub = (r - 2304) % 72;
            in = (j == 0 ? Wfb : Wgb) + (size_t)l * 73728;
            out = wl + ((j == 0) ? 2555904 : 2629632); K = 96; N = 768;
        } else if (r < 2592) {
            const int j = (r - 2448) / 72; sub = (r - 2448) % 72;
            in = (j == 0 ? Wfa : Wga) + (size_t)l * 73728;
            out = wl + ((j == 0) ? 1769472 : 1843200); K = 768; N = 96;
        } else if (r < 2784) {
            const int e = (r - 2592) * 256 + threadIdx.x;   // 49152 total
            const int n = e / 768, kk = e - n * 768;
            const float* wb = Wb + (size_t)l * 6144;
            (wl + 1916928)[(size_t)n * 768 + kk] =
                (n < 8) ? f2bf(wb[(size_t)kk * 8 + n]) : (unsigned short)0;
            return;
        } else {
            const int rr = r - 2784;
            const int j = rr / 1536; sub = rr % 1536;
            if (j == 0)      { in = Wgate + (size_t)l * 1572864; out = wl + 2703360; K = 768; N = 2048; }
            else if (j == 1) { in = Wup   + (size_t)l * 1572864; out = wl + 4276224; K = 768; N = 2048; }
            else             { in = Wdown + (size_t)l * 1572864; out = wl + 5849088; K = 2048; N = 768; }
        }
    }
    __shared__ float t32[32][33];
    const int tx = threadIdx.x & 31, ty = threadIdx.x >> 5;
    const int nbx = N / 32;
    const int bx = sub % nbx, by = sub / nbx;
    const int k0 = by * 32, n0 = bx * 32;
#pragma unroll
    for (int i = 0; i < 4; ++i)
        t32[ty + i * 8][tx] = in[(size_t)(k0 + ty + i * 8) * N + n0 + tx];
    __syncthreads();
#pragma unroll
    for (int i = 0; i < 4; ++i)
        out[(size_t)(n0 + ty + i * 8) * K + k0 + tx] = f2bf(t32[tx][ty + i * 8]);
}

// ---------------------------------------------------------------- bf16 MFMA GEMM (XCD-swizzled)
enum { BE_BIASB = 0, BE_BF16, BE_RESB, BE_RESF };

template <int EPI, int NH>
__global__ __launch_bounds__(256)
void bgemm(const unsigned short* __restrict__ A, const unsigned short* __restrict__ Bt,
           float* Cf, unsigned short* Cb,
           const float* P0, const float* P1,
           int M, int N, int K)
{
    __shared__ unsigned short As[NH][128 * 32];
    __shared__ unsigned short Bs[NH][128 * 32];
    const int tid = threadIdx.x;
    const int w = tid >> 6, l = tid & 63;
    const int wm = w >> 1, wn = w & 1;
    const int lr = l & 15, lh = l >> 4;
    const int nwg = gridDim.x * gridDim.y;
    const int wg = xcd_swz(blockIdx.y * gridDim.x + blockIdx.x, nwg);
    const int m0 = (wg / gridDim.x) * 128, n0 = (wg % gridDim.x) * 128;

    f32x4 acc[4][4];
#pragma unroll
    for (int i = 0; i < 4; ++i)
#pragma unroll
        for (int j = 0; j < 4; ++j) acc[i][j] = (f32x4){0.f, 0.f, 0.f, 0.f};

    const int sr = l >> 2, sq = (l & 3) * 8;
    const unsigned short* Ag = A + (size_t)(m0 + w * 32 + sr) * K + sq;
    const unsigned short* Bg = Bt + (size_t)(n0 + w * 32 + sr) * K + sq;
    const int lofs = (w * 32) * 32;

    for (int kt = 0; kt < K; kt += 32 * NH) {
        __syncthreads();
#pragma unroll
        for (int hh = 0; hh < NH; ++hh) {
            gload16(Ag + kt + hh * 32, &As[hh][lofs]);
            gload16(Ag + kt + hh * 32 + 16 * (size_t)K, &As[hh][lofs + 16 * 32]);
            gload16(Bg + kt + hh * 32, &Bs[hh][lofs]);
            gload16(Bg + kt + hh * 32 + 16 * (size_t)K, &Bs[hh][lofs + 16 * 32]);
        }
        __syncthreads();
#pragma unroll
        for (int hh = 0; hh < NH; ++hh) {
            bf16x8 af[4], bfv[4];
#pragma unroll
            for (int mi = 0; mi < 4; ++mi)
                af[mi] = *(const bf16x8*)&As[hh][(wm * 64 + mi * 16 + lr) * 32 + lh * 8];
#pragma unroll
            for (int ni = 0; ni < 4; ++ni)
                bfv[ni] = *(const bf16x8*)&Bs[hh][(wn * 64 + ni * 16 + lr) * 32 + lh * 8];
#pragma unroll
            for (int mi = 0; mi < 4; ++mi)
#pragma unroll
                for (int ni = 0; ni < 4; ++ni)
                    acc[mi][ni] = __builtin_amdgcn_mfma_f32_16x16x32_bf16(af[mi], bfv[ni], acc[mi][ni], 0, 0, 0);
        }
    }

#pragma unroll
    for (int mi = 0; mi < 4; ++mi) {
#pragma unroll
        for (int j = 0; j < 4; ++j) {
            const int row = m0 + wm * 64 + mi * 16 + lh * 4 + j;
#pragma unroll
            for (int ni = 0; ni < 4; ++ni) {
                const int col = n0 + wn * 64 + ni * 16 + lr;
                const size_t idx = (size_t)row * N + col;
                float v = acc[mi][ni][j];
                if constexpr (EPI == BE_BIASB) { Cb[idx] = f2bf(v + P0[col]); }
                else if constexpr (EPI == BE_BF16) { Cb[idx] = f2bf(v); }
                else if constexpr (EPI == BE_RESB) {
                    Cb[idx] = f2bf(v + bf2f(((const unsigned short*)P0)[idx]));
                }
                else if constexpr (EPI == BE_RESF) {
                    Cf[idx] = v + bf2f(((const unsigned short*)P0)[idx]);
                }
            }
        }
    }
}

// QKV + fa/ga/beta fused GEMM: N = 2560 = [Wq|Wk|Wv|Wfa|Wga|Wb|pad]^T
// NH=3 (BK=96); L2-supertiled: per-XCD chunk = 8m x (2 groups of 10n)
__global__ __launch_bounds__(256)
void bgemm_qkvfg(const unsigned short* __restrict__ A, const unsigned short* __restrict__ Bt,
                 unsigned short* __restrict__ Cq, unsigned short* __restrict__ Ck,
                 unsigned short* __restrict__ Cv, unsigned short* __restrict__ Cfa,
                 unsigned short* __restrict__ Cga, float* __restrict__ bout, int K)
{
    constexpr int N = 2560;
    __shared__ unsigned short As[3][128 * 32];
    __shared__ unsigned short Bs[3][128 * 32];
    const int tid = threadIdx.x;
    const int w = tid >> 6, l = tid & 63;
    const int wm = w >> 1, wn = w & 1;
    const int lr = l & 15, lh = l >> 4;
    // supertile decode: grid (20,64) = 1280 wgs; chunk/XCD = 160 = 2 x (8m x 10n)
    const int orig = blockIdx.y * gridDim.x + blockIdx.x;
    const int c = orig & 7, lid = orig >> 3;           // lid in [0,160)
    const int sg = lid / 80, r2 = lid % 80;
    const int mm = r2 / 10, nn = r2 % 10;
    const int m0 = (c * 8 + mm) * 128, n0 = (sg * 10 + nn) * 128;

    f32x4 acc[4][4];
#pragma unroll
    for (int i = 0; i < 4; ++i)
#pragma unroll
        for (int j = 0; j < 4; ++j) acc[i][j] = (f32x4){0.f, 0.f, 0.f, 0.f};

    const int sr = l >> 2, sq = (l & 3) * 8;
    const unsigned short* Ag = A + (size_t)(m0 + w * 32 + sr) * K + sq;
    const unsigned short* Bg = Bt + (size_t)(n0 + w * 32 + sr) * K + sq;
    const int lofs = (w * 32) * 32;

    for (int kt = 0; kt < K; kt += 96) {
        __syncthreads();
#pragma unroll
        for (int hh = 0; hh < 3; ++hh) {
            gload16(Ag + kt + hh * 32, &As[hh][lofs]);
            gload16(Ag + kt + hh * 32 + 16 * (size_t)K, &As[hh][lofs + 16 * 32]);
            gload16(Bg + kt + hh * 32, &Bs[hh][lofs]);
            gload16(Bg + kt + hh * 32 + 16 * (size_t)K, &Bs[hh][lofs + 16 * 32]);
        }
        __syncthreads();
#pragma unroll
        for (int hh = 0; hh < 3; ++hh) {
            bf16x8 af[4], bfv[4];
#pragma unroll
            for (int mi = 0; mi < 4; ++mi)
                af[mi] = *(const bf16x8*)&As[hh][(wm * 64 + mi * 16 + lr) * 32 + lh * 8];
#pragma unroll
            for (int ni = 0; ni < 4; ++ni)
                bfv[ni] = *(const bf16x8*)&Bs[hh][(wn * 64 + ni * 16 + lr) * 32 + lh * 8];
#pragma unroll
            for (int mi = 0; mi < 4; ++mi)
#pragma unroll
                for (int ni = 0; ni < 4; ++ni)
                    acc[mi][ni] = __builtin_amdgcn_mfma_f32_16x16x32_bf16(af[mi], bfv[ni], acc[mi][ni], 0, 0, 0);
        }
    }

#pragma unroll
    for (int mi = 0; mi < 4; ++mi) {
#pragma unroll
        for (int j = 0; j < 4; ++j) {
            const int row = m0 + wm * 64 + mi * 16 + lh * 4 + j;
#pragma unroll
            for (int ni = 0; ni < 4; ++ni) {
                const int col = n0 + wn * 64 + ni * 16 + lr;
                const float v = acc[mi][ni][j];
                if (col < 2304) {
                    const int tgt = col / 768;
                    const int cl = col - tgt * 768;
                    unsigned short* dst = (tgt == 0) ? Cq : (tgt == 1) ? Ck : Cv;
                    dst[(size_t)row * 768 + cl] = f2bf(silu_f(v));
                } else if (col < 2400) {
                    Cfa[(size_t)row * HD + (col - 2304)] = f2bf(v);
                } else if (col < 2496) {
                    Cga[(size_t)row * HD + (col - 2400)] = f2bf(v);
                } else if (col < 2504) {
                    bout[(size_t)row * HH + (col - 2496)] = 1.f / (1.f + __expf(-v));
                }
                // cols 2504..2559: discard
            }
        }
    }
}

// Dual-B GEMM for SwiGLU (BK=96, 128x64 dual tile, L2-supertiled)
__global__ __launch_bounds__(256)
void bgemm_dual(const unsigned short* __restrict__ A,
                const unsigned short* __restrict__ Bg_, const unsigned short* __restrict__ Bu_,
                unsigned short* __restrict__ C, int M, int N, int K)
{
    __shared__ unsigned short As[3][128 * 32];
    __shared__ unsigned short Bs1[3][64 * 32];
    __shared__ unsigned short Bs2[3][64 * 32];
    const int tid = threadIdx.x;
    const int w = tid >> 6, l = tid & 63;
    const int wm = w >> 1, wn = w & 1;
    const int lr = l & 15, lh = l >> 4;
    // supertile decode: grid (32,64) = 2048 wgs; chunk/XCD = 256 = 4 x (8m x 8n)
    const int orig = blockIdx.y * gridDim.x + blockIdx.x;
    const int c = orig & 7, lid = orig >> 3;           // lid in [0,256)
    const int sg = lid >> 6, r2 = lid & 63;
    const int mm = r2 >> 3, nn = r2 & 7;
    const int m0 = (c * 8 + mm) * 128, n0 = (sg * 8 + nn) * 64;

    f32x4 a1[4][2], a2[4][2];
#pragma unroll
    for (int i = 0; i < 4; ++i)
#pragma unroll
        for (int j = 0; j < 2; ++j) { a1[i][j] = (f32x4){0.f,0.f,0.f,0.f}; a2[i][j] = (f32x4){0.f,0.f,0.f,0.f}; }

    const int sr = l >> 2, sq = (l & 3) * 8;
    const unsigned short* Ag  = A   + (size_t)(m0 + w * 32 + sr) * K + sq;
    const unsigned short* B1g = Bg_ + (size_t)(n0 + w * 16 + sr) * K + sq;
    const unsigned short* B2g = Bu_ + (size_t)(n0 + w * 16 + sr) * K + sq;
    const int aofs = (w * 32) * 32;
    const int bofs = (w * 16) * 32;

    for (int kt = 0; kt < K; kt += 96) {
        __syncthreads();
#pragma unroll
        for (int hh = 0; hh < 3; ++hh) {
            gload16(Ag + kt + hh * 32, &As[hh][aofs]);
            gload16(Ag + kt + hh * 32 + 16 * (size_t)K, &As[hh][aofs + 16 * 32]);
            gload16(B1g + kt + hh * 32, &Bs1[hh][bofs]);
            gload16(B2g + kt + hh * 32, &Bs2[hh][bofs]);
        }
        __syncthreads();
#pragma unroll
        for (int hh = 0; hh < 3; ++hh) {
            bf16x8 af[4], b1[2], b2[2];
#pragma unroll
            for (int mi = 0; mi < 4; ++mi)
                af[mi] = *(const bf16x8*)&As[hh][(wm * 64 + mi * 16 + lr) * 32 + lh * 8];
#pragma unroll
            for (int ni = 0; ni < 2; ++ni) {
                b1[ni] = *(const bf16x8*)&Bs1[hh][(wn * 32 + ni * 16 + lr) * 32 + lh * 8];
                b2[ni] = *(const bf16x8*)&Bs2[hh][(wn * 32 + ni * 16 + lr) * 32 + lh * 8];
            }
#pragma unroll
            for (int mi = 0; mi < 4; ++mi)
#pragma unroll
                for (int ni = 0; ni < 2; ++ni) {
                    a1[mi][ni] = __builtin_amdgcn_mfma_f32_16x16x32_bf16(af[mi], b1[ni], a1[mi][ni], 0, 0, 0);
                    a2[mi][ni] = __builtin_amdgcn_mfma_f32_16x16x32_bf16(af[mi], b2[ni], a2[mi][ni], 0, 0, 0);
                }
        }
    }

#pragma unroll
    for (int mi = 0; mi < 4; ++mi)
#pragma unroll
        for (int j = 0; j < 4; ++j) {
            const int row = m0 + wm * 64 + mi * 16 + lh * 4 + j;
#pragma unroll
            for (int ni = 0; ni < 2; ++ni) {
                const int col = n0 + wn * 32 + ni * 16 + lr;
                const float g = a1[mi][ni][j], u = a2[mi][ni][j];
                C[(size_t)row * N + col] = f2bf(silu_f(g) * u);
            }
        }
}

// ---------------------------------------------------------------- KDA chunkwise precompute
constexpr int TBP = 72;   // Tb row pad (u16)
constexpr int XLP = 72;   // Xall/Xl row pad (u16)
__global__ __launch_bounds__(256)
void kda_pre(const unsigned short* __restrict__ q, const unsigned short* __restrict__ k,
             unsigned short* v,
             const unsigned short* __restrict__ fab, const float* __restrict__ Alog,
             const float* __restrict__ dtb, const unsigned short* __restrict__ wfb,
             const float* __restrict__ beta,
             unsigned short* __restrict__ ol, float* __restrict__ Bc,
             unsigned short* __restrict__ Wbf, unsigned short* __restrict__ Ktg,
             unsigned short* __restrict__ qeb)
{
    __shared__ unsigned short Kb[CH * KP];   // k (bf16), then kappa_tilde (bf16)
    __shared__ float Qp[CH * RP];            // g -> L -> q'
    __shared__ float sb[CH];
    __shared__ float qn[CH], kn[CH];
    __shared__ float ct[HD];
    __shared__ __align__(16) char uR[36864];
    unsigned short* Kk   = (unsigned short*)uR;
    unsigned short* Xall = (unsigned short*)uR;
    unsigned short* Abf  = (unsigned short*)(uR + 27648);
    unsigned short* Tb   = (unsigned short*)(uR + 27648);
    unsigned short* Xl   = (unsigned short*)uR;

    const int blk = blockIdx.x;
    const int ch = blk & 31, bh = blk >> 5;
    const int b = bh >> 3, h = bh & 7;
    const int tid = threadIdx.x;
    const size_t base = (size_t)b * (TT * HH * HD) + (size_t)(ch * CH) * (HH * HD) + h * HD;
    const size_t tok0 = (size_t)b * TT + ch * CH;

    // P0: stage k (bf16 direct copy), beta
    for (int e = tid; e < CH * 12; e += 256) {
        const int t = e / 12, c8 = (e % 12) * 8;
        *(u16x8*)&Kb[t * KP + c8] = *(const u16x8*)(k + base + (size_t)t * 768 + c8);
    }
    if (tid < CH) sb[tid] = beta[((size_t)b * TT + ch * CH + tid) * HH + h];

    // P0b (MFMA, fused EG): g = -exp(A_log)*softplus(fab@Wfb_h + dt_bias) -> Qp
    {
        const int lane = tid & 63, w = tid >> 6;
        const int lr = lane & 15, lh = lane >> 4;
        const int t0 = w * 16;
        bf16x8 afr[3];
#pragma unroll
        for (int ks = 0; ks < 3; ++ks)
            afr[ks] = *(const bf16x8*)(fab + (tok0 + t0 + lr) * HD + ks * 32 + lh * 8);
#pragma unroll
        for (int nt = 0; nt < 6; ++nt) {
            f32x4 acc = (f32x4){0.f, 0.f, 0.f, 0.f};
#pragma unroll
            for (int ks = 0; ks < 3; ++ks) {
                const bf16x8 bfr = *(const bf16x8*)(wfb +
                    (size_t)(h * HD + nt * 16 + lr) * HD + ks * 32 + lh * 8);
                acc = __builtin_amdgcn_mfma_f32_16x16x32_bf16(afr[ks], bfr, acc, 0, 0, 0);
            }
            const int c = nt * 16 + lr;
            const float na = -__expf(Alog[h * HD + c]);
            const float db = dtb[h * HD + c];
#pragma unroll
            for (int r = 0; r < 4; ++r) {
                const int t = t0 + lh * 4 + r;
                const float lin = acc[r] + db;
                const float sp = (lin > 20.f) ? lin : __logf(1.f + __expf(lin));
                Qp[t * RP + c] = na * sp;
            }
        }
    }
    __syncthreads();

    // P1n: fused l2norm factors (q bf16 from global, k from staged Kb)
    {
        const int t = tid >> 2, s = tid & 3;
        float ssq = 0.f, ssk = 0.f;
#pragma unroll
        for (int i = 0; i < 3; ++i) {
            const u16x8 qv8 = *(const u16x8*)(q + base + (size_t)t * 768 + s * 24 + i * 8);
            const u16x8 kv8 = *(const u16x8*)&Kb[t * KP + s * 24 + i * 8];
#pragma unroll
            for (int j2 = 0; j2 < 8; ++j2) {
                const float qv = bf2f(qv8[j2]);
                const float kv = bf2f(kv8[j2]);
                ssq = fmaf(qv, qv, ssq);
                ssk = fmaf(kv, kv, ssk);
            }
        }
        ssq += __shfl_xor(ssq, 1); ssq += __shfl_xor(ssq, 2);
        ssk += __shfl_xor(ssk, 1); ssk += __shfl_xor(ssk, 2);
        if (s == 0) {
            qn[t] = rsqrtf(ssq + 1e-6f) * 0.1020620726159658f;
            kn[t] = rsqrtf(ssk + 1e-6f);
        }
    }

    // P1 stage A: 2-level cumsum — halves of 32
    if (tid < 192) {
        const int c = tid % 96;
        const int hf = tid / 96;
        const int ts = hf * 32;
        float L = 0.f;
        for (int t = ts; t < ts + 32; ++t) { L += Qp[t * RP + c]; Qp[t * RP + c] = L; }
        if (hf == 0) ct[c] = L;
    }
    __syncthreads();
    // P1 stage B: add half-0 totals to half-1
    if (tid >= 96 && tid < 192) {
        const int c = tid - 96;
        const float off = ct[c];
        for (int t = 32; t < 64; ++t) Qp[t * RP + c] += off;
    }
    __syncthreads();

    // P2: kappa, kappa_tilde (bf16), q', Bc  (l2norm factors applied here)
    for (int e = tid; e < CH * HD; e += 256) {
        const int t = e / HD, c = e % HD;
        const float L = Qp[t * RP + c];
        const float B = __expf(L), iB = __expf(-L);
        const float kv = bf2f(Kb[t * KP + c]) * kn[t];
        if (t == CH - 1) Bc[((size_t)bh * NCH + ch) * HD + c] = B;
        Kk[t * KP + c] = f2bf(kv * B);
        const unsigned short kti = f2bf(kv * iB);
        const float qv = bf2f(q[base + (size_t)t * 768 + c]) * qn[t];
        Kb[t * KP + c] = kti;
        Qp[t * RP + c] = qv * B;                  // q'
    }
    __syncthreads();

    // P2b: export ktil^T -> Ktg[(bh,ch)][c][t]
#pragma unroll
    for (int i = 0; i < 3; ++i) {
        const int u = i * 256 + tid;
        const int c = u / 8, t8 = (u % 8) * 8;
        u16x8 vv;
#pragma unroll
        for (int j = 0; j < 8; ++j) vv[j] = Kb[(t8 + j) * KP + c];
        *(u16x8*)(Ktg + (((size_t)bh * NCH + ch) * HD + c) * CH + t8) = vv;
    }

    // P3 (MFMA): A[t][i] = beta_t * (kappa_t . ktil_i), i < t  (bf16 -> Abf)
    {
        const int lane = tid & 63;
        const int lr = lane & 15, lh = lane >> 4;
        const int t0 = (tid >> 6) * 16;
        bf16x8 afr[3];
#pragma unroll
        for (int ks = 0; ks < 3; ++ks)
            afr[ks] = *(const bf16x8*)&Kk[(t0 + lr) * KP + ks * 32 + lh * 8];
#pragma unroll
        for (int i0 = 0; i0 < 64; i0 += 16) {
            f32x4 acc = (f32x4){0.f, 0.f, 0.f, 0.f};
#pragma unroll
            for (int ks = 0; ks < 3; ++ks) {
                const bf16x8 bfr = *(const bf16x8*)&Kb[(i0 + lr) * KP + ks * 32 + lh * 8];
                acc = __builtin_amdgcn_mfma_f32_16x16x32_bf16(afr[ks], bfr, acc, 0, 0, 0);
            }
#pragma unroll
            for (int r = 0; r < 4; ++r) {
                const int t = t0 + lh * 4 + r;
                const int i = i0 + lr;
                Abf[t * 72 + i] = (i < t) ? f2bf(acc[r] * sb[t]) : (unsigned short)0;
            }
        }
    }
    __syncthreads();

    // P4: blocked forward solve. rhs from v (bf16) / Kk.
    float X[CH];
    const int j = tid;
    if (j < 192) {
        if (j < HD) {
#pragma unroll
            for (int t = 0; t < CH; ++t) X[t] = sb[t] * bf2f(v[base + (size_t)t * 768 + j]);
        } else {
#pragma unroll
            for (int t = 0; t < CH; ++t) X[t] = sb[t] * bf2f(Kk[t * KP + (j - HD)]);
        }
    }
    __syncthreads();                 // all Kk reads done
    for (int e = tid; e < 192 * XLP; e += 256) Xall[e] = 0;
    __syncthreads();

#pragma unroll
    for (int p = 0; p < 4; ++p) {
        if (p > 0) {
            const int lane = tid & 63, w = tid >> 6;
            const int lr = lane & 15, lh = lane >> 4;
#pragma unroll
            for (int e = 0; e < 3; ++e) {
                const int col0 = (w * 3 + e) * 16;
                f32x4 uacc = (f32x4){0.f, 0.f, 0.f, 0.f};
#pragma unroll
                for (int q2 = 0; q2 < 2; ++q2) {
                    const bf16x8 aa = *(const bf16x8*)&Abf[(p * 16 + lr) * 72 + q2 * 32 + lh * 8];
                    const bf16x8 xx = *(const bf16x8*)&Xall[(col0 + lr) * XLP + q2 * 32 + lh * 8];
                    uacc = __builtin_amdgcn_mfma_f32_16x16x32_bf16(aa, xx, uacc, 0, 0, 0);
                }
#pragma unroll
                for (int r = 0; r < 4; ++r)
                    Xall[(col0 + lr) * XLP + p * 16 + lh * 4 + r] = f2bf(uacc[r]);
            }
            __syncthreads();
        }
        if (j < 192) {
            if (p > 0) {
                const u16x8 c0 = *(const u16x8*)&Xall[j * XLP + p * 16];
                const u16x8 c1 = *(const u16x8*)&Xall[j * XLP + p * 16 + 8];
#pragma unroll
                for (int rr = 0; rr < 8; ++rr) {
                    X[p * 16 + rr]     -= bf2f(c0[rr]);
                    X[p * 16 + 8 + rr] -= bf2f(c1[rr]);
                }
            }
#pragma unroll
            for (int tr = 0; tr < 16; ++tr) {
                float a = 0.f;
#pragma unroll
                for (int i = 0; i < 16; ++i)
                    if (i < tr)
                        a = fmaf(bf2f(Abf[(p * 16 + tr) * 72 + p * 16 + i]), X[p * 16 + i], a);
                X[p * 16 + tr] -= a;
            }
            u16x8 s0, s1;
#pragma unroll
            for (int rr = 0; rr < 8; ++rr) {
                s0[rr] = f2bf(X[p * 16 + rr]);
                s1[rr] = f2bf(X[p * 16 + 8 + rr]);
            }
            *(u16x8*)&Xall[j * XLP + p * 16] = s0;
            *(u16x8*)&Xall[j * XLP + p * 16 + 8] = s1;
        }
        __syncthreads();
    }

    // P5: store U (bf16, in-place over v) / -W (bf16)
    if (j < 192) {
        if (j < HD) {
#pragma unroll
            for (int t = 0; t < CH; ++t) v[base + (size_t)t * 768 + j] = f2bf(X[t]);
        } else {
#pragma unroll
            for (int t = 0; t < CH; ++t) Wbf[base + (size_t)t * 768 + (j - HD)] = f2bf(-X[t]);
        }
    }
    __syncthreads();   // Abf dead past here (Tb reuses); Xall stays live as Xl

    // P6 (MFMA): T[t][i] = q'_t . ktil_i, i <= t -> Tb
    {
        const int lane = tid & 63;
        const int lr = lane & 15, lh = lane >> 4;
        const int t0 = (tid >> 6) * 16;
        bf16x8 afr[3];
#pragma unroll
        for (int ks = 0; ks < 3; ++ks) {
            const float4 qa = *(const float4*)&Qp[(t0 + lr) * RP + ks * 32 + lh * 8];
            const float4 qc = *(const float4*)&Qp[(t0 + lr) * RP + ks * 32 + lh * 8 + 4];
            bf16x8 a;
            a[0] = (short)f2bf(qa.x); a[1] = (short)f2bf(qa.y);
            a[2] = (short)f2bf(qa.z); a[3] = (short)f2bf(qa.w);
            a[4] = (short)f2bf(qc.x); a[5] = (short)f2bf(qc.y);
            a[6] = (short)f2bf(qc.z); a[7] = (short)f2bf(qc.w);
            afr[ks] = a;
        }
#pragma unroll
        for (int i0 = 0; i0 < 64; i0 += 16) {
            f32x4 acc = (f32x4){0.f, 0.f, 0.f, 0.f};
#pragma unroll
            for (int ks = 0; ks < 3; ++ks) {
                const bf16x8 bfr = *(const bf16x8*)&Kb[(i0 + lr) * KP + ks * 32 + lh * 8];
                acc = __builtin_amdgcn_mfma_f32_16x16x32_bf16(afr[ks], bfr, acc, 0, 0, 0);
            }
#pragma unroll
            for (int r = 0; r < 4; ++r) {
                const int t = t0 + lh * 4 + r;
                const int i = i0 + lr;
                Tb[t * TBP + i] = (i <= t) ? f2bf(acc[r]) : (unsigned short)0;
            }
        }
    }
    __syncthreads();

    // P7 (MFMA): res = T @ X (Xl == Xall) ; j<96 -> Ol ; j>=96 -> Qe(bf16)
    {
        const int lane = tid & 63;
        const int lr = lane & 15, lh = lane >> 4;
        const int w = tid >> 6;
        const int t0 = w * 16;
        bf16x8 af0 = *(const bf16x8*)&Tb[(t0 + lr) * TBP + lh * 8];
        bf16x8 af1 = *(const bf16x8*)&Tb[(t0 + lr) * TBP + 32 + lh * 8];
#pragma unroll
        for (int nt = 0; nt < 12; ++nt) {
            const int n0 = nt * 16;
            f32x4 acc = (f32x4){0.f, 0.f, 0.f, 0.f};
            acc = __builtin_amdgcn_mfma_f32_16x16x32_bf16(
                af0, *(const bf16x8*)&Xl[(n0 + lr) * XLP + lh * 8], acc, 0, 0, 0);
            acc = __builtin_amdgcn_mfma_f32_16x16x32_bf16(
                af1, *(const bf16x8*)&Xl[(n0 + lr) * XLP + 32 + lh * 8], acc, 0, 0, 0);
            const int jc = n0 + lr;
#pragma unroll
            for (int r = 0; r < 4; ++r) {
                const int t = t0 + lh * 4 + r;
                if (jc < HD) ol[base + (size_t)t * 768 + jc] = f2bf(acc[r]);
                else         qeb[base + (size_t)t * 768 + (jc - HD)] = f2bf(Qp[t * RP + (jc - HD)] - acc[r]);
            }
        }
    }
}

// ---------------------------------------------------------------- KDA sequential recurrence (MFMA, dbuf, 2 barriers/chunk)
constexpr int VSL = 16;
constexpr int WNP = 120;  // Wn row pad (u16)
constexpr int KTP2 = 72;  // Kt row pad
constexpr int DBP = 72;   // Dbt row pad
constexpr int SBP = 120;  // Sbt row pad
__global__ __launch_bounds__(256)
void kda_seq(const unsigned short* __restrict__ Wbf, const unsigned short* __restrict__ Ktg,
             const unsigned short* __restrict__ U, const float* __restrict__ Bc,
             unsigned short* __restrict__ SinT, float* __restrict__ states)
{
    __shared__ unsigned short Wn[2][CH * WNP];    // -W bf16, [t][k]
    __shared__ unsigned short Kt[2][HD * KTP2];   // ktil^T bf16, [k][t]
    __shared__ unsigned short Dbt[VSL * DBP];     // delta^T bf16, [v][t]
    __shared__ unsigned short Sbt[VSL * SBP];     // S^T bf16, [v][k]

    const int blk = blockIdx.x;
    const int bh = blk / 6, vq = blk - bh * 6;
    const int b = bh >> 3, h = bh & 7;
    const int tid = threadIdx.x;
    const int w = tid >> 6, lane = tid & 63;
    const int lr = lane & 15, lh = lane >> 4;
    const int v0 = vq * VSL;
    const size_t base = (size_t)b * (TT * HH * HD) + h * HD;
    const size_t cbase = (size_t)bh * NCH;

    const int t0 = w * 16;
    const int k1 = w * 16;
    const int k2 = (w < 2) ? (4 + w) * 16 : -1;

    f32x4 accS1 = (f32x4){0.f, 0.f, 0.f, 0.f};
    f32x4 accS2 = (f32x4){0.f, 0.f, 0.f, 0.f};

    for (int e = tid; e < VSL * SBP; e += 256) Sbt[e] = 0;

    u16x8 wpf[3], kpf[3];
    float upf[4], ucur[4];
    int cur = 0;

    // ---- stage chunk 0 into buf0
    {
        const size_t cb = base;
#pragma unroll
        for (int i = 0; i < 3; ++i) {
            const int u = i * 256 + tid;
            const int r = u / 12, c8 = (u % 12) * 8;
            wpf[i] = *(const u16x8*)(Wbf + cb + (size_t)r * 768 + c8);
        }
        const size_t kb_ = (cbase * HD) * CH;
#pragma unroll
        for (int i = 0; i < 3; ++i) {
            const int u = i * 256 + tid;
            const int c = u / 8, t8 = (u % 8) * 8;
            kpf[i] = *(const u16x8*)(Ktg + kb_ + (size_t)c * CH + t8);
        }
#pragma unroll
        for (int r = 0; r < 4; ++r)
            ucur[r] = bf2f(U[cb + (size_t)(t0 + lh * 4 + r) * 768 + v0 + lr]);
#pragma unroll
        for (int i = 0; i < 3; ++i) {
            const int u = i * 256 + tid;
            const int r = u / 12, c8 = (u % 12) * 8;
            *(u16x8*)&Wn[0][r * WNP + c8] = wpf[i];
        }
#pragma unroll
        for (int i = 0; i < 3; ++i) {
            const int u = i * 256 + tid;
            const int c = u / 8, t8 = (u % 8) * 8;
            *(u16x8*)&Kt[0][c * KTP2 + t8] = kpf[i];
        }
    }
    __syncthreads();

    for (int ch = 0; ch < NCH; ++ch) {
        if (ch + 1 < NCH) {
            const size_t cb = base + (size_t)((ch + 1) * CH) * (HH * HD);
#pragma unroll
            for (int i = 0; i < 3; ++i) {
                const int u = i * 256 + tid;
                const int r = u / 12, c8 = (u % 12) * 8;
                wpf[i] = *(const u16x8*)(Wbf + cb + (size_t)r * 768 + c8);
            }
            const size_t kb_ = ((cbase + ch + 1) * HD) * CH;
#pragma unroll
            for (int i = 0; i < 3; ++i) {
                const int u = i * 256 + tid;
                const int c = u / 8, t8 = (u % 8) * 8;
                kpf[i] = *(const u16x8*)(Ktg + kb_ + (size_t)c * CH + t8);
            }
#pragma unroll
            for (int r = 0; r < 4; ++r)
                upf[r] = bf2f(U[cb + (size_t)(t0 + lh * 4 + r) * 768 + v0 + lr]);
        }

        // store S_in (bf16 S^T slice) for the O-epilogue
        if (tid < 192) {
            const int row = tid / 12, c8 = (tid % 12) * 8;
            *(u16x8*)(SinT + (size_t)(cbase + ch) * 9216 + (size_t)(v0 + row) * 96 + c8)
                = *(const u16x8*)&Sbt[row * SBP + c8];
        }

        // step A: delta = U + (-W)@S
        f32x4 del = (f32x4){ucur[0], ucur[1], ucur[2], ucur[3]};
#pragma unroll
        for (int ks = 0; ks < 3; ++ks) {
            const bf16x8 a = *(const bf16x8*)&Wn[cur][(t0 + lr) * WNP + ks * 32 + lh * 8];
            const bf16x8 bb = *(const bf16x8*)&Sbt[lr * SBP + ks * 32 + lh * 8];
            del = __builtin_amdgcn_mfma_f32_16x16x32_bf16(a, bb, del, 0, 0, 0);
        }
#pragma unroll
        for (int r = 0; r < 4; ++r)
            Dbt[lr * DBP + t0 + lh * 4 + r] = f2bf(del[r]);
        __syncthreads();   // bar1: Dbt visible; Sbt stepA reads done

        // step B: S = Bc * (S + ktil^T @ delta)
        const float* bc = Bc + (cbase + ch) * HD;
#pragma unroll
        for (int ks = 0; ks < 2; ++ks) {
            const bf16x8 a = *(const bf16x8*)&Kt[cur][(k1 + lr) * KTP2 + ks * 32 + lh * 8];
            const bf16x8 bb = *(const bf16x8*)&Dbt[lr * DBP + ks * 32 + lh * 8];
            accS1 = __builtin_amdgcn_mfma_f32_16x16x32_bf16(a, bb, accS1, 0, 0, 0);
        }
#pragma unroll
        for (int r = 0; r < 4; ++r) accS1[r] *= bc[k1 + lh * 4 + r];
        if (k2 >= 0) {
#pragma unroll
            for (int ks = 0; ks < 2; ++ks) {
                const bf16x8 a = *(const bf16x8*)&Kt[cur][(k2 + lr) * KTP2 + ks * 32 + lh * 8];
                const bf16x8 bb = *(const bf16x8*)&Dbt[lr * DBP + ks * 32 + lh * 8];
                accS2 = __builtin_amdgcn_mfma_f32_16x16x32_bf16(a, bb, accS2, 0, 0, 0);
            }
#pragma unroll
            for (int r = 0; r < 4; ++r) accS2[r] *= bc[k2 + lh * 4 + r];
        }

        // export S -> Sbt (safe after bar1); stage next chunk into buf^1
#pragma unroll
        for (int r = 0; r < 4; ++r)
            Sbt[lr * SBP + k1 + lh * 4 + r] = f2bf(accS1[r]);
        if (k2 >= 0) {
#pragma unroll
            for (int r = 0; r < 4; ++r)
                Sbt[lr * SBP + k2 + lh * 4 + r] = f2bf(accS2[r]);
        }
        if (ch + 1 < NCH) {
            const int nxt = cur ^ 1;
#pragma unroll
            for (int i = 0; i < 3; ++i) {
                const int u = i * 256 + tid;
                const int r = u / 12, c8 = (u % 12) * 8;
                *(u16x8*)&Wn[nxt][r * WNP + c8] = wpf[i];
            }
#pragma unroll
            for (int i = 0; i < 3; ++i) {
                const int u = i * 256 + tid;
                const int c = u / 8, t8 = (u % 8) * 8;
                *(u16x8*)&Kt[nxt][c * KTP2 + t8] = kpf[i];
            }
#pragma unroll
            for (int r = 0; r < 4; ++r) ucur[r] = upf[r];
        }
        __syncthreads();   // bar2
        cur ^= 1;
    }

    // final states (f32)
    {
        float* sp = states + (size_t)bh * (HD * HD);
#pragma unroll
        for (int r = 0; r < 4; ++r)
            sp[(size_t)(k1 + lh * 4 + r) * HD + v0 + lr] = accS1[r];
        if (k2 >= 0) {
#pragma unroll
            for (int r = 0; r < 4; ++r)
                sp[(size_t)(k2 + lh * 4 + r) * HD + v0 + lr] = accS2[r];
        }
    }
}

// ---------------------------------------------------------------- KDA parallel O epilogue (MFMA)
__global__ __launch_bounds__(256)
void kda_epi(const unsigned short* __restrict__ SinT, const unsigned short* __restrict__ Qe,
             const unsigned short* __restrict__ Ol,
             const unsigned short* __restrict__ gab, const unsigned short* __restrict__ wgb,
             const float* __restrict__ onw, unsigned short* __restrict__ obf)
{
    __shared__ unsigned short Sl[96 * 104];    // S^T bf16 [v][k]
    __shared__ unsigned short Ql[64 * 104];    // Qe bf16 [t][k]
    __shared__ unsigned short Olb[64 * 104];
    __shared__ float onws[HD];

    const int bx = blockIdx.x;
    const int bh = bx >> 5, ch = bx & 31;
    const int b = bh >> 3, h = bh & 7;
    const int tid = threadIdx.x;
    const size_t cb = (size_t)b * (TT * HH * HD) + (size_t)(ch * CH) * (HH * HD) + h * HD;
    const size_t sbase = (size_t)(bh * NCH + ch) * 9216;
    const size_t tok0 = (size_t)b * TT + ch * CH;

#pragma unroll
    for (int i = 0; i < 5; ++i) {
        const int u = i * 256 + tid;
        if (u < 1152) {
            const int row = u / 12, c8 = (u % 12) * 8;
            *(u16x8*)&Sl[row * 104 + c8] = *(const u16x8*)(SinT + sbase + (size_t)row * 96 + c8);
        }
    }
#pragma unroll
    for (int i = 0; i < 3; ++i) {
        const int u = i * 256 + tid;
        const int t = u / 12, c8 = (u % 12) * 8;
        *(u16x8*)&Ql[t * 104 + c8]  = *(const u16x8*)(Qe + cb + (size_t)t * 768 + c8);
        *(u16x8*)&Olb[t * 104 + c8] = *(const u16x8*)(Ol + cb + (size_t)t * 768 + c8);
    }
    if (tid < HD) onws[tid] = onw[tid];

    const int lane = tid & 63, w = tid >> 6;
    const int lr = lane & 15, lh = lane >> 4;
    const int t0 = w * 16;

    // fused gate GEMM (global operands, L2-hot): gacc[t][v] = gab @ Wgb_h
    bf16x8 gaf[3];
#pragma unroll
    for (int ks = 0; ks < 3; ++ks)
        gaf[ks] = *(const bf16x8*)(gab + (tok0 + t0 + lr) * HD + ks * 32 + lh * 8);
    f32x4 gacc[6];
#pragma unroll
    for (int nt = 0; nt < 6; ++nt) {
        gacc[nt] = (f32x4){0.f, 0.f, 0.f, 0.f};
#pragma unroll
        for (int ks = 0; ks < 3; ++ks) {
            const bf16x8 bfr = *(const bf16x8*)(wgb +
                (size_t)(h * HD + nt * 16 + lr) * HD + ks * 32 + lh * 8);
            gacc[nt] = __builtin_amdgcn_mfma_f32_16x16x32_bf16(gaf[ks], bfr, gacc[nt], 0, 0, 0);
        }
    }
    __syncthreads();

    bf16x8 af[3];
#pragma unroll
    for (int ks = 0; ks < 3; ++ks)
        af[ks] = *(const bf16x8*)&Ql[(t0 + lr) * 104 + ks * 32 + lh * 8];

    f32x4 acc[6];
#pragma unroll
    for (int nt = 0; nt < 6; ++nt) {
#pragma unroll
        for (int r = 0; r < 4; ++r)
            acc[nt][r] = bf2f(Olb[(t0 + lh * 4 + r) * 104 + nt * 16 + lr]);
#pragma unroll
        for (int ks = 0; ks < 3; ++ks)
            acc[nt] = __builtin_amdgcn_mfma_f32_16x16x32_bf16(
                af[ks], *(const bf16x8*)&Sl[(nt * 16 + lr) * 104 + ks * 32 + lh * 8],
                acc[nt], 0, 0, 0);
    }

    float ss0 = 0.f, ss1 = 0.f, ss2 = 0.f, ss3 = 0.f;
#pragma unroll
    for (int nt = 0; nt < 6; ++nt) {
        ss0 = fmaf(acc[nt][0], acc[nt][0], ss0);
        ss1 = fmaf(acc[nt][1], acc[nt][1], ss1);
        ss2 = fmaf(acc[nt][2], acc[nt][2], ss2);
        ss3 = fmaf(acc[nt][3], acc[nt][3], ss3);
    }
#pragma unroll
    for (int d = 1; d < 16; d <<= 1) {
        ss0 += __shfl_xor(ss0, d); ss1 += __shfl_xor(ss1, d);
        ss2 += __shfl_xor(ss2, d); ss3 += __shfl_xor(ss3, d);
    }
    const float rr0 = rsqrtf(ss0 * (1.f / HD) + 1e-6f);
    const float rr1 = rsqrtf(ss1 * (1.f / HD) + 1e-6f);
    const float rr2 = rsqrtf(ss2 * (1.f / HD) + 1e-6f);
    const float rr3 = rsqrtf(ss3 * (1.f / HD) + 1e-6f);

#pragma unroll
    for (int nt = 0; nt < 6; ++nt) {
        const int v = nt * 16 + lr;
        const float ow = onws[v];
#pragma unroll
        for (int r = 0; r < 4; ++r) {
            const int t = t0 + lh * 4 + r;
            const float rrv = (r == 0) ? rr0 : (r == 1) ? rr1 : (r == 2) ? rr2 : rr3;
            const float gg = gacc[nt][r];
            const float val = acc[nt][r] * rrv * ow * (gg / (1.f + __expf(-gg)));
            obf[cb + (size_t)t * 768 + v] = f2bf(val);
        }
    }
}

// ---------------------------------------------------------------- host
extern "C" void kernel_launch(void* const* d_in, const int* in_sizes, int n_in,
                              void* d_out, int out_size, void* d_ws, size_t ws_size,
                              hipStream_t stream)
{
    (void)in_sizes; (void)n_in; (void)out_size; (void)ws_size;
    const float* hidden   = (const float*)d_in[0];
    const float* mask     = (const float*)d_in[1];
    const float* norm_a_w = (const float*)d_in[2];
    const float* norm_a_b = (const float*)d_in[3];
    const float* proj_a_w = (const float*)d_in[4];
    const float* proj_a_b = (const float*)d_in[5];
    const float* ln_w     = (const float*)d_in[6];
    const float* ln_b     = (const float*)d_in[7];
    const float* Wq       = (const float*)d_in[8];
    const float* Wk       = (const float*)d_in[9];
    const float* Wv       = (const float*)d_in[10];
    const float* Wfa      = (const float*)d_in[11];
    const float* Wfb      = (const float*)d_in[12];
    const float* dt_bias  = (const float*)d_in[13];
    const float* A_log    = (const float*)d_in[14];
    const float* Wb       = (const float*)d_in[15];
    const float* Wga      = (const float*)d_in[16];
    const float* Wgb      = (const float*)d_in[17];
    const float* onorm_w  = (const float*)d_in[18];
    const float* Wo       = (const float*)d_in[19];
    const float* Wgate    = (const float*)d_in[20];
    const float* Wup      = (const float*)d_in[21];
    const float* Wdown    = (const float*)d_in[22];

    float* ws    = (float*)d_ws;
    float* hbuf  = ws;                 // bf16 residual stream
    float* qb    = ws + HROW;          // bf16 q; dead after pre -> mg lives here
    float* kb    = ws + 2 * HROW;      // bf16 k
    float* vb    = ws + 3 * HROW;      // bf16 v -> U(bf16) -> a_bf
    float* egb   = ws + 4 * HROW;      // SinT region
    float* betab = ws + 5 * HROW;                     // MM*HH
    float* BcP   = betab + (size_t)MM * HH;           // 32*32*96
    unsigned short* SinT = (unsigned short*)egb;      // 18.9MB
    unsigned short* hb16 = (unsigned short*)hbuf;
    unsigned short* q16 = (unsigned short*)qb;
    unsigned short* k16 = (unsigned short*)kb;
    unsigned short* v16 = (unsigned short*)vb;
    unsigned short* bfp = (unsigned short*)(BcP + 32 * NCH * HD);
    unsigned short* x_bf    = bfp;  bfp += HROW;
    unsigned short* fab_bf  = bfp;  bfp += (size_t)MM * HD;
    unsigned short* gab_bf  = bfp;  bfp += (size_t)MM * HD;
    unsigned short* olb_bf  = bfp;  bfp += HROW;
    unsigned short* w_bf    = bfp;  bfp += HROW;
    unsigned short* k_bf    = bfp;  bfp += HROW;      // ktil^T [bh][ch][96][64]
    unsigned short* qe_bf   = bfp;  bfp += HROW;      // Qe bf16
    unsigned short* wt_proj = bfp;  bfp += 589824;
    unsigned short *wt_qkv[LL], *wt_o[LL], *wt_fb[LL], *wt_gb[LL],
                   *wt_gate[LL], *wt_up[LL], *wt_down[LL];
    for (int l = 0; l < LL; ++l) {
        wt_qkv[l] = bfp;  bfp += 2560 * 768;  // [q|k|v|fa|ga|beta|pad] rows
        wt_o[l] = bfp;    bfp += 589824;
        wt_fb[l] = bfp;   bfp += 73728;
        wt_gb[l] = bfp;   bfp += 73728;
        wt_gate[l] = bfp; bfp += 1572864;
        wt_up[l] = bfp;   bfp += 1572864;
        wt_down[l] = bfp; bfp += 1572864;
    }
    unsigned short* mg_bf = (unsigned short*)qb;    // q/k dead after pre
    unsigned short* a_bf  = (unsigned short*)vb;    // U dead after seq

    float* out    = (float*)d_out;
    float* states = out + HROW;

    // weight transpose+convert: ONE dispatch for everything
    transcvt_all<<<15360, 256, 0, stream>>>(proj_a_w, Wq, Wk, Wv, Wo, Wfb, Wgb,
                                            Wfa, Wga, Wb, Wgate, Wup, Wdown, wt_proj);

    layernorm_rows<<<MM, 256, 0, stream>>>(hidden, x_bf, norm_a_w, norm_a_b, nullptr);
    // h = LN(hidden)@proj + b  -> bf16 residual stream
    bgemm<BE_BIASB, 3><<<dim3(6, 64), 256, 0, stream>>>(x_bf, wt_proj, nullptr, hb16,
                                                        proj_a_b, nullptr, MM, DD, DD);

    for (int l = 0; l < LL; ++l) {
        layernorm_rows_b<<<MM, 256, 0, stream>>>(hb16, x_bf, ln_w + l * DD, ln_b + l * DD, mask);
        // fused q|k|v|fa|ga|beta in ONE GEMM (N=2560, BK=96, L2-supertiled)
        bgemm_qkvfg<<<dim3(20, 64), 256, 0, stream>>>(x_bf, wt_qkv[l], q16, k16, v16,
                                                      fab_bf, gab_bf, betab, DD);
        // chunkwise scan (EG + l2norm fused into pre; gate fused into epi)
        kda_pre<<<1024, 256, 0, stream>>>(q16, k16, v16, fab_bf, A_log + l * DD, dt_bias + l * DD,
                                          wt_fb[l], betab, olb_bf, BcP, w_bf, k_bf, qe_bf);
        kda_seq<<<192, 256, 0, stream>>>(w_bf, k_bf, v16, BcP, SinT,
                                         states + (size_t)l * BB * HH * HD * HD);
        kda_epi<<<1024, 256, 0, stream>>>(SinT, qe_bf, olb_bf, gab_bf, wt_gb[l],
                                          onorm_w + l * HD, x_bf);
        // a = o @ Wo (BK=96)
        bgemm<BE_BF16, 3><<<dim3(6, 64), 256, 0, stream>>>(x_bf, wt_o[l], nullptr, a_bf, nullptr, nullptr, MM, DD, DD);
        // swiglu (128x64 dual tile, BK=96, L2-supertiled)
        bgemm_dual<<<dim3(32, 64), 256, 0, stream>>>(a_bf, wt_gate[l], wt_up[l], mg_bf, MM, FF, DD);
        // h' = mg@Wdown + h : intermediate layer -> bf16 in-place; last layer -> f32 out
        if (l == LL - 1)
            bgemm<BE_RESF, 2><<<dim3(6, 64), 256, 0, stream>>>(mg_bf, wt_down[l], out, nullptr,
                                                               (const float*)hb16, nullptr, MM, DD, FF);
        else
            bgemm<BE_RESB, 2><<<dim3(6, 64), 256, 0, stream>>>(mg_bf, wt_down[l], nullptr, hb16,
                                                               (const float*)hb16, nullptr, MM, DD, FF);
    }
}

// Round 24
// 693.544 us; speedup vs baseline: 1.0299x; 1.0299x over previous
//
#include <hip/hip_runtime.h>
#include <cstddef>
#include <cstdint>
#include <cmath>

// Problem constants
constexpr int BB = 4, TT = 2048, DD = 768, HH = 8, HD = 96, FF = 2048, LL = 2;
constexpr int MM = BB * TT;              // 8192
constexpr size_t HROW = (size_t)MM * DD; // 6291456
constexpr int CH = 64;                   // scan chunk length
constexpr int NCH = TT / CH;             // 32 chunks per sequence
constexpr int RP = 100;                  // padded LDS row (floats)
constexpr int KP = 104;                  // padded LDS row (ushorts)

typedef float f32x4 __attribute__((ext_vector_type(4)));
typedef short bf16x8 __attribute__((ext_vector_type(8)));
typedef unsigned short u16x8 __attribute__((ext_vector_type(8)));

__device__ __forceinline__ void gload16(const void* g, void* l) {
    __builtin_amdgcn_global_load_lds(
        (const __attribute__((address_space(1))) void*)g,
        (__attribute__((address_space(3))) void*)l, 16, 0, 0);
}
__device__ __forceinline__ float bf2f(unsigned short u) {
    return __uint_as_float(((unsigned)u) << 16);
}
__device__ __forceinline__ unsigned short f2bf(float f) {
    unsigned u = __float_as_uint(f);
    unsigned r = (u + 0x7fffu + ((u >> 16) & 1u)) >> 16;
    return (unsigned short)r;
}
__device__ __forceinline__ float silu_f(float v) {
    return v / (1.f + __expf(-v));
}
// XCD-aware bijective swizzle of linear workgroup id (nwg % 8 == 0)
__device__ __forceinline__ int xcd_swz(int wg, int nwg) {
    return (wg & 7) * (nwg >> 3) + (wg >> 3);
}

// ---------------------------------------------------------------- LayerNorm (f32 in) -> bf16
__global__ __launch_bounds__(256)
void layernorm_rows(const float* __restrict__ x, unsigned short* __restrict__ y,
                    const float* __restrict__ w, const float* __restrict__ b,
                    const float* mask)
{
    const int row = blockIdx.x;
    const int tid = threadIdx.x;
    const float* xr = x + (size_t)row * DD;
    float v0 = xr[tid], v1 = xr[tid + 256], v2 = xr[tid + 512];
    float s = v0 + v1 + v2;
    float ss = v0 * v0 + v1 * v1 + v2 * v2;
#pragma unroll
    for (int i = 1; i < 64; i <<= 1) { s += __shfl_xor(s, i); ss += __shfl_xor(ss, i); }
    __shared__ float red[8];
    const int wid = tid >> 6, lane = tid & 63;
    if (lane == 0) { red[wid] = s; red[4 + wid] = ss; }
    __syncthreads();
    const float S  = red[0] + red[1] + red[2] + red[3];
    const float SS = red[4] + red[5] + red[6] + red[7];
    const float mean = S * (1.f / DD);
    const float var  = SS * (1.f / DD) - mean * mean;
    const float rstd = rsqrtf(var + 1e-5f);
    const float m = mask ? mask[row] : 1.f;
    unsigned short* yr = y + (size_t)row * DD;
    yr[tid]       = f2bf(((v0 - mean) * rstd * w[tid]       + b[tid])       * m);
    yr[tid + 256] = f2bf(((v1 - mean) * rstd * w[tid + 256] + b[tid + 256]) * m);
    yr[tid + 512] = f2bf(((v2 - mean) * rstd * w[tid + 512] + b[tid + 512]) * m);
}

// ---------------------------------------------------------------- LayerNorm (bf16 in) -> bf16
__global__ __launch_bounds__(256)
void layernorm_rows_b(const unsigned short* __restrict__ x, unsigned short* __restrict__ y,
                      const float* __restrict__ w, const float* __restrict__ b,
                      const float* mask)
{
    const int row = blockIdx.x;
    const int tid = threadIdx.x;
    const unsigned short* xr = x + (size_t)row * DD;
    float v0 = bf2f(xr[tid]), v1 = bf2f(xr[tid + 256]), v2 = bf2f(xr[tid + 512]);
    float s = v0 + v1 + v2;
    float ss = v0 * v0 + v1 * v1 + v2 * v2;
#pragma unroll
    for (int i = 1; i < 64; i <<= 1) { s += __shfl_xor(s, i); ss += __shfl_xor(ss, i); }
    __shared__ float red[8];
    const int wid = tid >> 6, lane = tid & 63;
    if (lane == 0) { red[wid] = s; red[4 + wid] = ss; }
    __syncthreads();
    const float S  = red[0] + red[1] + red[2] + red[3];
    const float SS = red[4] + red[5] + red[6] + red[7];
    const float mean = S * (1.f / DD);
    const float var  = SS * (1.f / DD) - mean * mean;
    const float rstd = rsqrtf(var + 1e-5f);
    const float m = mask ? mask[row] : 1.f;
    unsigned short* yr = y + (size_t)row * DD;
    yr[tid]       = f2bf(((v0 - mean) * rstd * w[tid]       + b[tid])       * m);
    yr[tid + 256] = f2bf(((v1 - mean) * rstd * w[tid + 256] + b[tid + 256]) * m);
    yr[tid + 512] = f2bf(((v2 - mean) * rstd * w[tid + 512] + b[tid + 512]) * m);
}

// ---------------------------------------------------------------- batched transpose+convert
__global__ __launch_bounds__(256)
void transcvt_all(const float* __restrict__ proj,
                  const float* __restrict__ Wq, const float* __restrict__ Wk,
                  const float* __restrict__ Wv, const float* __restrict__ Wo,
                  const float* __restrict__ Wfb, const float* __restrict__ Wgb,
                  const float* __restrict__ Wfa, const float* __restrict__ Wga,
                  const float* __restrict__ Wb, const float* __restrict__ Wgate,
                  const float* __restrict__ Wup, const float* __restrict__ Wdown,
                  unsigned short* __restrict__ wt)
{
    const int bid = blockIdx.x;
    const float* in; unsigned short* out; int K, N, sub;
    if (bid < 576) { in = proj; out = wt; K = 768; N = 768; sub = bid; }
    else {
        const int rem = bid - 576;
        const int l = rem / 7392, r = rem - l * 7392;
        unsigned short* wl = wt + 589824 + (size_t)l * 7421952;
        if (r < 2304) {
            const int j = r / 576; sub = r % 576;
            in = (j == 0 ? Wq : j == 1 ? Wk : j == 2 ? Wv : Wo) + (size_t)l * 589824;
            out = (j < 3) ? (wl + (size_t)j * 589824) : (wl + 1966080);
            K = 768; N = 768;
        } else if (r < 2448) {
            const int j = (r - 2304) / 72; sub = (r - 2304) % 72;
            in = (j == 0 ? Wfb : Wgb) + (size_t)l * 73728;
            out = wl + ((j == 0) ? 2555904 : 2629632); K = 96; N = 768;
        } else if (r < 2592) {
            const int j = (r - 2448) / 72; sub = (r - 2448) % 72;
            in = (j == 0 ? Wfa : Wga) + (size_t)l * 73728;
            out = wl + ((j == 0) ? 1769472 : 1843200); K = 768; N = 96;
        } else if (r < 2784) {
            const int e = (r - 2592) * 256 + threadIdx.x;   // 49152 total
            const int n = e / 768, kk = e - n * 768;
            const float* wb = Wb + (size_t)l * 6144;
            (wl + 1916928)[(size_t)n * 768 + kk] =
                (n < 8) ? f2bf(wb[(size_t)kk * 8 + n]) : (unsigned short)0;
            return;
        } else {
            const int rr = r - 2784;
            const int j = rr / 1536; sub = rr % 1536;
            if (j == 0)      { in = Wgate + (size_t)l * 1572864; out = wl + 2703360; K = 768; N = 2048; }
            else if (j == 1) { in = Wup   + (size_t)l * 1572864; out = wl + 4276224; K = 768; N = 2048; }
            else             { in = Wdown + (size_t)l * 1572864; out = wl + 5849088; K = 2048; N = 768; }
        }
    }
    __shared__ float t32[32][33];
    const int tx = threadIdx.x & 31, ty = threadIdx.x >> 5;
    const int nbx = N / 32;
    const int bx = sub % nbx, by = sub / nbx;
    const int k0 = by * 32, n0 = bx * 32;
#pragma unroll
    for (int i = 0; i < 4; ++i)
        t32[ty + i * 8][tx] = in[(size_t)(k0 + ty + i * 8) * N + n0 + tx];
    __syncthreads();
#pragma unroll
    for (int i = 0; i < 4; ++i)
        out[(size_t)(n0 + ty + i * 8) * K + k0 + tx] = f2bf(t32[tx][ty + i * 8]);
}

// ---------------------------------------------------------------- bf16 MFMA GEMM (XCD-swizzled)
enum { BE_BIASB = 0, BE_BF16, BE_RESB, BE_RESF };

template <int EPI, int NH>
__global__ __launch_bounds__(256)
void bgemm(const unsigned short* __restrict__ A, const unsigned short* __restrict__ Bt,
           float* Cf, unsigned short* Cb,
           const float* P0, const float* P1,
           int M, int N, int K)
{
    __shared__ unsigned short As[NH][128 * 32];
    __shared__ unsigned short Bs[NH][128 * 32];
    const int tid = threadIdx.x;
    const int w = tid >> 6, l = tid & 63;
    const int wm = w >> 1, wn = w & 1;
    const int lr = l & 15, lh = l >> 4;
    const int nwg = gridDim.x * gridDim.y;
    const int wg = xcd_swz(blockIdx.y * gridDim.x + blockIdx.x, nwg);
    const int m0 = (wg / gridDim.x) * 128, n0 = (wg % gridDim.x) * 128;

    f32x4 acc[4][4];
#pragma unroll
    for (int i = 0; i < 4; ++i)
#pragma unroll
        for (int j = 0; j < 4; ++j) acc[i][j] = (f32x4){0.f, 0.f, 0.f, 0.f};

    const int sr = l >> 2, sq = (l & 3) * 8;
    const unsigned short* Ag = A + (size_t)(m0 + w * 32 + sr) * K + sq;
    const unsigned short* Bg = Bt + (size_t)(n0 + w * 32 + sr) * K + sq;
    const int lofs = (w * 32) * 32;

    for (int kt = 0; kt < K; kt += 32 * NH) {
        __syncthreads();
#pragma unroll
        for (int hh = 0; hh < NH; ++hh) {
            gload16(Ag + kt + hh * 32, &As[hh][lofs]);
            gload16(Ag + kt + hh * 32 + 16 * (size_t)K, &As[hh][lofs + 16 * 32]);
            gload16(Bg + kt + hh * 32, &Bs[hh][lofs]);
            gload16(Bg + kt + hh * 32 + 16 * (size_t)K, &Bs[hh][lofs + 16 * 32]);
        }
        __syncthreads();
#pragma unroll
        for (int hh = 0; hh < NH; ++hh) {
            bf16x8 af[4], bfv[4];
#pragma unroll
            for (int mi = 0; mi < 4; ++mi)
                af[mi] = *(const bf16x8*)&As[hh][(wm * 64 + mi * 16 + lr) * 32 + lh * 8];
#pragma unroll
            for (int ni = 0; ni < 4; ++ni)
                bfv[ni] = *(const bf16x8*)&Bs[hh][(wn * 64 + ni * 16 + lr) * 32 + lh * 8];
#pragma unroll
            for (int mi = 0; mi < 4; ++mi)
#pragma unroll
                for (int ni = 0; ni < 4; ++ni)
                    acc[mi][ni] = __builtin_amdgcn_mfma_f32_16x16x32_bf16(af[mi], bfv[ni], acc[mi][ni], 0, 0, 0);
        }
    }

#pragma unroll
    for (int mi = 0; mi < 4; ++mi) {
#pragma unroll
        for (int j = 0; j < 4; ++j) {
            const int row = m0 + wm * 64 + mi * 16 + lh * 4 + j;
#pragma unroll
            for (int ni = 0; ni < 4; ++ni) {
                const int col = n0 + wn * 64 + ni * 16 + lr;
                const size_t idx = (size_t)row * N + col;
                float v = acc[mi][ni][j];
                if constexpr (EPI == BE_BIASB) { Cb[idx] = f2bf(v + P0[col]); }
                else if constexpr (EPI == BE_BF16) { Cb[idx] = f2bf(v); }
                else if constexpr (EPI == BE_RESB) {
                    Cb[idx] = f2bf(v + bf2f(((const unsigned short*)P0)[idx]));
                }
                else if constexpr (EPI == BE_RESF) {
                    Cf[idx] = v + bf2f(((const unsigned short*)P0)[idx]);
                }
            }
        }
    }
}

// QKV + fa/ga/beta fused GEMM: N = 2560 = [Wq|Wk|Wv|Wfa|Wga|Wb|pad]^T
// BK=64; L2-supertiled: per-XCD chunk = 2 x (8m x 10n)
__global__ __launch_bounds__(256)
void bgemm_qkvfg(const unsigned short* __restrict__ A, const unsigned short* __restrict__ Bt,
                 unsigned short* __restrict__ Cq, unsigned short* __restrict__ Ck,
                 unsigned short* __restrict__ Cv, unsigned short* __restrict__ Cfa,
                 unsigned short* __restrict__ Cga, float* __restrict__ bout, int K)
{
    constexpr int N = 2560;
    __shared__ unsigned short As[2][128 * 32];
    __shared__ unsigned short Bs[2][128 * 32];
    const int tid = threadIdx.x;
    const int w = tid >> 6, l = tid & 63;
    const int wm = w >> 1, wn = w & 1;
    const int lr = l & 15, lh = l >> 4;
    // supertile decode: grid (20,64) = 1280 wgs; chunk/XCD = 160 = 2 x (8m x 10n)
    const int orig = blockIdx.y * gridDim.x + blockIdx.x;
    const int c = orig & 7, lid = orig >> 3;           // lid in [0,160)
    const int sg = lid / 80, r2 = lid % 80;
    const int mm = r2 / 10, nn = r2 % 10;
    const int m0 = (c * 8 + mm) * 128, n0 = (sg * 10 + nn) * 128;

    f32x4 acc[4][4];
#pragma unroll
    for (int i = 0; i < 4; ++i)
#pragma unroll
        for (int j = 0; j < 4; ++j) acc[i][j] = (f32x4){0.f, 0.f, 0.f, 0.f};

    const int sr = l >> 2, sq = (l & 3) * 8;
    const unsigned short* Ag = A + (size_t)(m0 + w * 32 + sr) * K + sq;
    const unsigned short* Bg = Bt + (size_t)(n0 + w * 32 + sr) * K + sq;
    const int lofs = (w * 32) * 32;

    for (int kt = 0; kt < K; kt += 64) {
        __syncthreads();
#pragma unroll
        for (int hh = 0; hh < 2; ++hh) {
            gload16(Ag + kt + hh * 32, &As[hh][lofs]);
            gload16(Ag + kt + hh * 32 + 16 * (size_t)K, &As[hh][lofs + 16 * 32]);
            gload16(Bg + kt + hh * 32, &Bs[hh][lofs]);
            gload16(Bg + kt + hh * 32 + 16 * (size_t)K, &Bs[hh][lofs + 16 * 32]);
        }
        __syncthreads();
#pragma unroll
        for (int hh = 0; hh < 2; ++hh) {
            bf16x8 af[4], bfv[4];
#pragma unroll
            for (int mi = 0; mi < 4; ++mi)
                af[mi] = *(const bf16x8*)&As[hh][(wm * 64 + mi * 16 + lr) * 32 + lh * 8];
#pragma unroll
            for (int ni = 0; ni < 4; ++ni)
                bfv[ni] = *(const bf16x8*)&Bs[hh][(wn * 64 + ni * 16 + lr) * 32 + lh * 8];
#pragma unroll
            for (int mi = 0; mi < 4; ++mi)
#pragma unroll
                for (int ni = 0; ni < 4; ++ni)
                    acc[mi][ni] = __builtin_amdgcn_mfma_f32_16x16x32_bf16(af[mi], bfv[ni], acc[mi][ni], 0, 0, 0);
        }
    }

#pragma unroll
    for (int mi = 0; mi < 4; ++mi) {
#pragma unroll
        for (int j = 0; j < 4; ++j) {
            const int row = m0 + wm * 64 + mi * 16 + lh * 4 + j;
#pragma unroll
            for (int ni = 0; ni < 4; ++ni) {
                const int col = n0 + wn * 64 + ni * 16 + lr;
                const float v = acc[mi][ni][j];
                if (col < 2304) {
                    const int tgt = col / 768;
                    const int cl = col - tgt * 768;
                    unsigned short* dst = (tgt == 0) ? Cq : (tgt == 1) ? Ck : Cv;
                    dst[(size_t)row * 768 + cl] = f2bf(silu_f(v));
                } else if (col < 2400) {
                    Cfa[(size_t)row * HD + (col - 2304)] = f2bf(v);
                } else if (col < 2496) {
                    Cga[(size_t)row * HD + (col - 2400)] = f2bf(v);
                } else if (col < 2504) {
                    bout[(size_t)row * HH + (col - 2496)] = 1.f / (1.f + __expf(-v));
                }
                // cols 2504..2559: discard
            }
        }
    }
}

// Dual-B GEMM for SwiGLU (BK=64, 128x64 dual tile, L2-supertiled)
__global__ __launch_bounds__(256)
void bgemm_dual(const unsigned short* __restrict__ A,
                const unsigned short* __restrict__ Bg_, const unsigned short* __restrict__ Bu_,
                unsigned short* __restrict__ C, int M, int N, int K)
{
    __shared__ unsigned short As[2][128 * 32];
    __shared__ unsigned short Bs1[2][64 * 32];
    __shared__ unsigned short Bs2[2][64 * 32];
    const int tid = threadIdx.x;
    const int w = tid >> 6, l = tid & 63;
    const int wm = w >> 1, wn = w & 1;
    const int lr = l & 15, lh = l >> 4;
    // supertile decode: grid (32,64) = 2048 wgs; chunk/XCD = 256 = 4 x (8m x 8n)
    const int orig = blockIdx.y * gridDim.x + blockIdx.x;
    const int c = orig & 7, lid = orig >> 3;           // lid in [0,256)
    const int sg = lid >> 6, r2 = lid & 63;
    const int mm = r2 >> 3, nn = r2 & 7;
    const int m0 = (c * 8 + mm) * 128, n0 = (sg * 8 + nn) * 64;

    f32x4 a1[4][2], a2[4][2];
#pragma unroll
    for (int i = 0; i < 4; ++i)
#pragma unroll
        for (int j = 0; j < 2; ++j) { a1[i][j] = (f32x4){0.f,0.f,0.f,0.f}; a2[i][j] = (f32x4){0.f,0.f,0.f,0.f}; }

    const int sr = l >> 2, sq = (l & 3) * 8;
    const unsigned short* Ag  = A   + (size_t)(m0 + w * 32 + sr) * K + sq;
    const unsigned short* B1g = Bg_ + (size_t)(n0 + w * 16 + sr) * K + sq;
    const unsigned short* B2g = Bu_ + (size_t)(n0 + w * 16 + sr) * K + sq;
    const int aofs = (w * 32) * 32;
    const int bofs = (w * 16) * 32;

    for (int kt = 0; kt < K; kt += 64) {
        __syncthreads();
#pragma unroll
        for (int hh = 0; hh < 2; ++hh) {
            gload16(Ag + kt + hh * 32, &As[hh][aofs]);
            gload16(Ag + kt + hh * 32 + 16 * (size_t)K, &As[hh][aofs + 16 * 32]);
            gload16(B1g + kt + hh * 32, &Bs1[hh][bofs]);
            gload16(B2g + kt + hh * 32, &Bs2[hh][bofs]);
        }
        __syncthreads();
#pragma unroll
        for (int hh = 0; hh < 2; ++hh) {
            bf16x8 af[4], b1[2], b2[2];
#pragma unroll
            for (int mi = 0; mi < 4; ++mi)
                af[mi] = *(const bf16x8*)&As[hh][(wm * 64 + mi * 16 + lr) * 32 + lh * 8];
#pragma unroll
            for (int ni = 0; ni < 2; ++ni) {
                b1[ni] = *(const bf16x8*)&Bs1[hh][(wn * 32 + ni * 16 + lr) * 32 + lh * 8];
                b2[ni] = *(const bf16x8*)&Bs2[hh][(wn * 32 + ni * 16 + lr) * 32 + lh * 8];
            }
#pragma unroll
            for (int mi = 0; mi < 4; ++mi)
#pragma unroll
                for (int ni = 0; ni < 2; ++ni) {
                    a1[mi][ni] = __builtin_amdgcn_mfma_f32_16x16x32_bf16(af[mi], b1[ni], a1[mi][ni], 0, 0, 0);
                    a2[mi][ni] = __builtin_amdgcn_mfma_f32_16x16x32_bf16(af[mi], b2[ni], a2[mi][ni], 0, 0, 0);
                }
        }
    }

#pragma unroll
    for (int mi = 0; mi < 4; ++mi)
#pragma unroll
        for (int j = 0; j < 4; ++j) {
            const int row = m0 + wm * 64 + mi * 16 + lh * 4 + j;
#pragma unroll
            for (int ni = 0; ni < 2; ++ni) {
                const int col = n0 + wn * 32 + ni * 16 + lr;
                const float g = a1[mi][ni][j], u = a2[mi][ni][j];
                C[(size_t)row * N + col] = f2bf(silu_f(g) * u);
            }
        }
}

// ---------------------------------------------------------------- KDA chunkwise precompute
constexpr int TBP = 72;   // Tb row pad (u16)
constexpr int XLP = 72;   // Xall/Xl row pad (u16)
__global__ __launch_bounds__(256)
void kda_pre(const unsigned short* __restrict__ q, const unsigned short* __restrict__ k,
             unsigned short* v,
             const unsigned short* __restrict__ fab, const float* __restrict__ Alog,
             const float* __restrict__ dtb, const unsigned short* __restrict__ wfb,
             const float* __restrict__ beta,
             unsigned short* __restrict__ ol, float* __restrict__ Bc,
             unsigned short* __restrict__ Wbf, unsigned short* __restrict__ Ktg,
             unsigned short* __restrict__ qeb)
{
    __shared__ unsigned short Kb[CH * KP];   // k (bf16), then kappa_tilde (bf16)
    __shared__ float Qp[CH * RP];            // g -> L -> q'
    __shared__ float sb[CH];
    __shared__ float qn[CH], kn[CH];
    __shared__ float ct[HD];
    __shared__ __align__(16) char uR[36864];
    unsigned short* Kk   = (unsigned short*)uR;
    unsigned short* Xall = (unsigned short*)uR;
    unsigned short* Abf  = (unsigned short*)(uR + 27648);
    unsigned short* Tb   = (unsigned short*)(uR + 27648);
    unsigned short* Xl   = (unsigned short*)uR;

    const int blk = blockIdx.x;
    const int ch = blk & 31, bh = blk >> 5;
    const int b = bh >> 3, h = bh & 7;
    const int tid = threadIdx.x;
    const size_t base = (size_t)b * (TT * HH * HD) + (size_t)(ch * CH) * (HH * HD) + h * HD;
    const size_t tok0 = (size_t)b * TT + ch * CH;

    // P0: stage k (bf16 direct copy), beta
    for (int e = tid; e < CH * 12; e += 256) {
        const int t = e / 12, c8 = (e % 12) * 8;
        *(u16x8*)&Kb[t * KP + c8] = *(const u16x8*)(k + base + (size_t)t * 768 + c8);
    }
    if (tid < CH) sb[tid] = beta[((size_t)b * TT + ch * CH + tid) * HH + h];

    // P0b (MFMA, fused EG): g = -exp(A_log)*softplus(fab@Wfb_h + dt_bias) -> Qp
    {
        const int lane = tid & 63, w = tid >> 6;
        const int lr = lane & 15, lh = lane >> 4;
        const int t0 = w * 16;
        bf16x8 afr[3];
#pragma unroll
        for (int ks = 0; ks < 3; ++ks)
            afr[ks] = *(const bf16x8*)(fab + (tok0 + t0 + lr) * HD + ks * 32 + lh * 8);
#pragma unroll
        for (int nt = 0; nt < 6; ++nt) {
            f32x4 acc = (f32x4){0.f, 0.f, 0.f, 0.f};
#pragma unroll
            for (int ks = 0; ks < 3; ++ks) {
                const bf16x8 bfr = *(const bf16x8*)(wfb +
                    (size_t)(h * HD + nt * 16 + lr) * HD + ks * 32 + lh * 8);
                acc = __builtin_amdgcn_mfma_f32_16x16x32_bf16(afr[ks], bfr, acc, 0, 0, 0);
            }
            const int c = nt * 16 + lr;
            const float na = -__expf(Alog[h * HD + c]);
            const float db = dtb[h * HD + c];
#pragma unroll
            for (int r = 0; r < 4; ++r) {
                const int t = t0 + lh * 4 + r;
                const float lin = acc[r] + db;
                const float sp = (lin > 20.f) ? lin : __logf(1.f + __expf(lin));
                Qp[t * RP + c] = na * sp;
            }
        }
    }
    __syncthreads();

    // P1n: fused l2norm factors (q bf16 from global, k from staged Kb)
    {
        const int t = tid >> 2, s = tid & 3;
        float ssq = 0.f, ssk = 0.f;
#pragma unroll
        for (int i = 0; i < 3; ++i) {
            const u16x8 qv8 = *(const u16x8*)(q + base + (size_t)t * 768 + s * 24 + i * 8);
            const u16x8 kv8 = *(const u16x8*)&Kb[t * KP + s * 24 + i * 8];
#pragma unroll
            for (int j2 = 0; j2 < 8; ++j2) {
                const float qv = bf2f(qv8[j2]);
                const float kv = bf2f(kv8[j2]);
                ssq = fmaf(qv, qv, ssq);
                ssk = fmaf(kv, kv, ssk);
            }
        }
        ssq += __shfl_xor(ssq, 1); ssq += __shfl_xor(ssq, 2);
        ssk += __shfl_xor(ssk, 1); ssk += __shfl_xor(ssk, 2);
        if (s == 0) {
            qn[t] = rsqrtf(ssq + 1e-6f) * 0.1020620726159658f;
            kn[t] = rsqrtf(ssk + 1e-6f);
        }
    }

    // P1 stage A: 2-level cumsum — halves of 32
    if (tid < 192) {
        const int c = tid % 96;
        const int hf = tid / 96;
        const int ts = hf * 32;
        float L = 0.f;
        for (int t = ts; t < ts + 32; ++t) { L += Qp[t * RP + c]; Qp[t * RP + c] = L; }
        if (hf == 0) ct[c] = L;
    }
    __syncthreads();
    // P1 stage B: add half-0 totals to half-1
    if (tid >= 96 && tid < 192) {
        const int c = tid - 96;
        const float off = ct[c];
        for (int t = 32; t < 64; ++t) Qp[t * RP + c] += off;
    }
    __syncthreads();

    // P2: kappa, kappa_tilde (bf16), q', Bc  (l2norm factors applied here)
    for (int e = tid; e < CH * HD; e += 256) {
        const int t = e / HD, c = e % HD;
        const float L = Qp[t * RP + c];
        const float B = __expf(L), iB = __expf(-L);
        const float kv = bf2f(Kb[t * KP + c]) * kn[t];
        if (t == CH - 1) Bc[((size_t)bh * NCH + ch) * HD + c] = B;
        Kk[t * KP + c] = f2bf(kv * B);
        const unsigned short kti = f2bf(kv * iB);
        const float qv = bf2f(q[base + (size_t)t * 768 + c]) * qn[t];
        Kb[t * KP + c] = kti;
        Qp[t * RP + c] = qv * B;                  // q'
    }
    __syncthreads();

    // P2b: export ktil^T -> Ktg[(bh,ch)][c][t]
#pragma unroll
    for (int i = 0; i < 3; ++i) {
        const int u = i * 256 + tid;
        const int c = u / 8, t8 = (u % 8) * 8;
        u16x8 vv;
#pragma unroll
        for (int j = 0; j < 8; ++j) vv[j] = Kb[(t8 + j) * KP + c];
        *(u16x8*)(Ktg + (((size_t)bh * NCH + ch) * HD + c) * CH + t8) = vv;
    }

    // P3 (MFMA): A[t][i] = beta_t * (kappa_t . ktil_i), i < t  (bf16 -> Abf)
    {
        const int lane = tid & 63;
        const int lr = lane & 15, lh = lane >> 4;
        const int t0 = (tid >> 6) * 16;
        bf16x8 afr[3];
#pragma unroll
        for (int ks = 0; ks < 3; ++ks)
            afr[ks] = *(const bf16x8*)&Kk[(t0 + lr) * KP + ks * 32 + lh * 8];
#pragma unroll
        for (int i0 = 0; i0 < 64; i0 += 16) {
            f32x4 acc = (f32x4){0.f, 0.f, 0.f, 0.f};
#pragma unroll
            for (int ks = 0; ks < 3; ++ks) {
                const bf16x8 bfr = *(const bf16x8*)&Kb[(i0 + lr) * KP + ks * 32 + lh * 8];
                acc = __builtin_amdgcn_mfma_f32_16x16x32_bf16(afr[ks], bfr, acc, 0, 0, 0);
            }
#pragma unroll
            for (int r = 0; r < 4; ++r) {
                const int t = t0 + lh * 4 + r;
                const int i = i0 + lr;
                Abf[t * 72 + i] = (i < t) ? f2bf(acc[r] * sb[t]) : (unsigned short)0;
            }
        }
    }
    __syncthreads();

    // P4: blocked forward solve. rhs from v (bf16) / Kk.
    float X[CH];
    const int j = tid;
    if (j < 192) {
        if (j < HD) {
#pragma unroll
            for (int t = 0; t < CH; ++t) X[t] = sb[t] * bf2f(v[base + (size_t)t * 768 + j]);
        } else {
#pragma unroll
            for (int t = 0; t < CH; ++t) X[t] = sb[t] * bf2f(Kk[t * KP + (j - HD)]);
        }
    }
    __syncthreads();                 // all Kk reads done
    for (int e = tid; e < 192 * XLP; e += 256) Xall[e] = 0;
    __syncthreads();

#pragma unroll
    for (int p = 0; p < 4; ++p) {
        if (p > 0) {
            const int lane = tid & 63, w = tid >> 6;
            const int lr = lane & 15, lh = lane >> 4;
#pragma unroll
            for (int e = 0; e < 3; ++e) {
                const int col0 = (w * 3 + e) * 16;
                f32x4 uacc = (f32x4){0.f, 0.f, 0.f, 0.f};
#pragma unroll
                for (int q2 = 0; q2 < 2; ++q2) {
                    const bf16x8 aa = *(const bf16x8*)&Abf[(p * 16 + lr) * 72 + q2 * 32 + lh * 8];
                    const bf16x8 xx = *(const bf16x8*)&Xall[(col0 + lr) * XLP + q2 * 32 + lh * 8];
                    uacc = __builtin_amdgcn_mfma_f32_16x16x32_bf16(aa, xx, uacc, 0, 0, 0);
                }
#pragma unroll
                for (int r = 0; r < 4; ++r)
                    Xall[(col0 + lr) * XLP + p * 16 + lh * 4 + r] = f2bf(uacc[r]);
            }
            __syncthreads();
        }
        if (j < 192) {
            if (p > 0) {
                const u16x8 c0 = *(const u16x8*)&Xall[j * XLP + p * 16];
                const u16x8 c1 = *(const u16x8*)&Xall[j * XLP + p * 16 + 8];
#pragma unroll
                for (int rr = 0; rr < 8; ++rr) {
                    X[p * 16 + rr]     -= bf2f(c0[rr]);
                    X[p * 16 + 8 + rr] -= bf2f(c1[rr]);
                }
            }
#pragma unroll
            for (int tr = 0; tr < 16; ++tr) {
                float a = 0.f;
#pragma unroll
                for (int i = 0; i < 16; ++i)
                    if (i < tr)
                        a = fmaf(bf2f(Abf[(p * 16 + tr) * 72 + p * 16 + i]), X[p * 16 + i], a);
                X[p * 16 + tr] -= a;
            }
            u16x8 s0, s1;
#pragma unroll
            for (int rr = 0; rr < 8; ++rr) {
                s0[rr] = f2bf(X[p * 16 + rr]);
                s1[rr] = f2bf(X[p * 16 + 8 + rr]);
            }
            *(u16x8*)&Xall[j * XLP + p * 16] = s0;
            *(u16x8*)&Xall[j * XLP + p * 16 + 8] = s1;
        }
        __syncthreads();
    }

    // P5: store U (bf16, in-place over v) / -W (bf16)
    if (j < 192) {
        if (j < HD) {
#pragma unroll
            for (int t = 0; t < CH; ++t) v[base + (size_t)t * 768 + j] = f2bf(X[t]);
        } else {
#pragma unroll
            for (int t = 0; t < CH; ++t) Wbf[base + (size_t)t * 768 + (j - HD)] = f2bf(-X[t]);
        }
    }
    __syncthreads();   // Abf dead past here (Tb reuses); Xall stays live as Xl

    // P6 (MFMA): T[t][i] = q'_t . ktil_i, i <= t -> Tb
    {
        const int lane = tid & 63;
        const int lr = lane & 15, lh = lane >> 4;
        const int t0 = (tid >> 6) * 16;
        bf16x8 afr[3];
#pragma unroll
        for (int ks = 0; ks < 3; ++ks) {
            const float4 qa = *(const float4*)&Qp[(t0 + lr) * RP + ks * 32 + lh * 8];
            const float4 qc = *(const float4*)&Qp[(t0 + lr) * RP + ks * 32 + lh * 8 + 4];
            bf16x8 a;
            a[0] = (short)f2bf(qa.x); a[1] = (short)f2bf(qa.y);
            a[2] = (short)f2bf(qa.z); a[3] = (short)f2bf(qa.w);
            a[4] = (short)f2bf(qc.x); a[5] = (short)f2bf(qc.y);
            a[6] = (short)f2bf(qc.z); a[7] = (short)f2bf(qc.w);
            afr[ks] = a;
        }
#pragma unroll
        for (int i0 = 0; i0 < 64; i0 += 16) {
            f32x4 acc = (f32x4){0.f, 0.f, 0.f, 0.f};
#pragma unroll
            for (int ks = 0; ks < 3; ++ks) {
                const bf16x8 bfr = *(const bf16x8*)&Kb[(i0 + lr) * KP + ks * 32 + lh * 8];
                acc = __builtin_amdgcn_mfma_f32_16x16x32_bf16(afr[ks], bfr, acc, 0, 0, 0);
            }
#pragma unroll
            for (int r = 0; r < 4; ++r) {
                const int t = t0 + lh * 4 + r;
                const int i = i0 + lr;
                Tb[t * TBP + i] = (i <= t) ? f2bf(acc[r]) : (unsigned short)0;
            }
        }
    }
    __syncthreads();

    // P7 (MFMA): res = T @ X (Xl == Xall) ; j<96 -> Ol ; j>=96 -> Qe(bf16)
    {
        const int lane = tid & 63;
        const int lr = lane & 15, lh = lane >> 4;
        const int w = tid >> 6;
        const int t0 = w * 16;
        bf16x8 af0 = *(const bf16x8*)&Tb[(t0 + lr) * TBP + lh * 8];
        bf16x8 af1 = *(const bf16x8*)&Tb[(t0 + lr) * TBP + 32 + lh * 8];
#pragma unroll
        for (int nt = 0; nt < 12; ++nt) {
            const int n0 = nt * 16;
            f32x4 acc = (f32x4){0.f, 0.f, 0.f, 0.f};
            acc = __builtin_amdgcn_mfma_f32_16x16x32_bf16(
                af0, *(const bf16x8*)&Xl[(n0 + lr) * XLP + lh * 8], acc, 0, 0, 0);
            acc = __builtin_amdgcn_mfma_f32_16x16x32_bf16(
                af1, *(const bf16x8*)&Xl[(n0 + lr) * XLP + 32 + lh * 8], acc, 0, 0, 0);
            const int jc = n0 + lr;
#pragma unroll
            for (int r = 0; r < 4; ++r) {
                const int t = t0 + lh * 4 + r;
                if (jc < HD) ol[base + (size_t)t * 768 + jc] = f2bf(acc[r]);
                else         qeb[base + (size_t)t * 768 + (jc - HD)] = f2bf(Qp[t * RP + (jc - HD)] - acc[r]);
            }
        }
    }
}

// ---------------------------------------------------------------- KDA sequential recurrence (MFMA, dbuf, 2 barriers/chunk)
constexpr int VSL = 16;
constexpr int WNP = 120;  // Wn row pad (u16)
constexpr int KTP2 = 72;  // Kt row pad
constexpr int DBP = 72;   // Dbt row pad
constexpr int SBP = 120;  // Sbt row pad
__global__ __launch_bounds__(256)
void kda_seq(const unsigned short* __restrict__ Wbf, const unsigned short* __restrict__ Ktg,
             const unsigned short* __restrict__ U, const float* __restrict__ Bc,
             unsigned short* __restrict__ SinT, float* __restrict__ states)
{
    __shared__ unsigned short Wn[2][CH * WNP];    // -W bf16, [t][k]
    __shared__ unsigned short Kt[2][HD * KTP2];   // ktil^T bf16, [k][t]
    __shared__ unsigned short Dbt[VSL * DBP];     // delta^T bf16, [v][t]
    __shared__ unsigned short Sbt[VSL * SBP];     // S^T bf16, [v][k]

    const int blk = blockIdx.x;
    const int bh = blk / 6, vq = blk - bh * 6;
    const int b = bh >> 3, h = bh & 7;
    const int tid = threadIdx.x;
    const int w = tid >> 6, lane = tid & 63;
    const int lr = lane & 15, lh = lane >> 4;
    const int v0 = vq * VSL;
    const size_t base = (size_t)b * (TT * HH * HD) + h * HD;
    const size_t cbase = (size_t)bh * NCH;

    const int t0 = w * 16;
    const int k1 = w * 16;
    const int k2 = (w < 2) ? (4 + w) * 16 : -1;

    f32x4 accS1 = (f32x4){0.f, 0.f, 0.f, 0.f};
    f32x4 accS2 = (f32x4){0.f, 0.f, 0.f, 0.f};

    for (int e = tid; e < VSL * SBP; e += 256) Sbt[e] = 0;

    u16x8 wpf[3], kpf[3];
    float upf[4], ucur[4];
    int cur = 0;

    // ---- stage chunk 0 into buf0
    {
        const size_t cb = base;
#pragma unroll
        for (int i = 0; i < 3; ++i) {
            const int u = i * 256 + tid;
            const int r = u / 12, c8 = (u % 12) * 8;
            wpf[i] = *(const u16x8*)(Wbf + cb + (size_t)r * 768 + c8);
        }
        const size_t kb_ = (cbase * HD) * CH;
#pragma unroll
        for (int i = 0; i < 3; ++i) {
            const int u = i * 256 + tid;
            const int c = u / 8, t8 = (u % 8) * 8;
            kpf[i] = *(const u16x8*)(Ktg + kb_ + (size_t)c * CH + t8);
        }
#pragma unroll
        for (int r = 0; r < 4; ++r)
            ucur[r] = bf2f(U[cb + (size_t)(t0 + lh * 4 + r) * 768 + v0 + lr]);
#pragma unroll
        for (int i = 0; i < 3; ++i) {
            const int u = i * 256 + tid;
            const int r = u / 12, c8 = (u % 12) * 8;
            *(u16x8*)&Wn[0][r * WNP + c8] = wpf[i];
        }
#pragma unroll
        for (int i = 0; i < 3; ++i) {
            const int u = i * 256 + tid;
            const int c = u / 8, t8 = (u % 8) * 8;
            *(u16x8*)&Kt[0][c * KTP2 + t8] = kpf[i];
        }
    }
    __syncthreads();

    for (int ch = 0; ch < NCH; ++ch) {
        if (ch + 1 < NCH) {
            const size_t cb = base + (size_t)((ch + 1) * CH) * (HH * HD);
#pragma unroll
            for (int i = 0; i < 3; ++i) {
                const int u = i * 256 + tid;
                const int r = u / 12, c8 = (u % 12) * 8;
                wpf[i] = *(const u16x8*)(Wbf + cb + (size_t)r * 768 + c8);
            }
            const size_t kb_ = ((cbase + ch + 1) * HD) * CH;
#pragma unroll
            for (int i = 0; i < 3; ++i) {
                const int u = i * 256 + tid;
                const int c = u / 8, t8 = (u % 8) * 8;
                kpf[i] = *(const u16x8*)(Ktg + kb_ + (size_t)c * CH + t8);
            }
#pragma unroll
            for (int r = 0; r < 4; ++r)
                upf[r] = bf2f(U[cb + (size_t)(t0 + lh * 4 + r) * 768 + v0 + lr]);
        }

        // store S_in (bf16 S^T slice) for the O-epilogue
        if (tid < 192) {
            const int row = tid / 12, c8 = (tid % 12) * 8;
            *(u16x8*)(SinT + (size_t)(cbase + ch) * 9216 + (size_t)(v0 + row) * 96 + c8)
                = *(const u16x8*)&Sbt[row * SBP + c8];
        }

        // step A: delta = U + (-W)@S
        f32x4 del = (f32x4){ucur[0], ucur[1], ucur[2], ucur[3]};
#pragma unroll
        for (int ks = 0; ks < 3; ++ks) {
            const bf16x8 a = *(const bf16x8*)&Wn[cur][(t0 + lr) * WNP + ks * 32 + lh * 8];
            const bf16x8 bb = *(const bf16x8*)&Sbt[lr * SBP + ks * 32 + lh * 8];
            del = __builtin_amdgcn_mfma_f32_16x16x32_bf16(a, bb, del, 0, 0, 0);
        }
#pragma unroll
        for (int r = 0; r < 4; ++r)
            Dbt[lr * DBP + t0 + lh * 4 + r] = f2bf(del[r]);
        __syncthreads();   // bar1: Dbt visible; Sbt stepA reads done

        // step B: S = Bc * (S + ktil^T @ delta)
        const float* bc = Bc + (cbase + ch) * HD;
#pragma unroll
        for (int ks = 0; ks < 2; ++ks) {
            const bf16x8 a = *(const bf16x8*)&Kt[cur][(k1 + lr) * KTP2 + ks * 32 + lh * 8];
            const bf16x8 bb = *(const bf16x8*)&Dbt[lr * DBP + ks * 32 + lh * 8];
            accS1 = __builtin_amdgcn_mfma_f32_16x16x32_bf16(a, bb, accS1, 0, 0, 0);
        }
#pragma unroll
        for (int r = 0; r < 4; ++r) accS1[r] *= bc[k1 + lh * 4 + r];
        if (k2 >= 0) {
#pragma unroll
            for (int ks = 0; ks < 2; ++ks) {
                const bf16x8 a = *(const bf16x8*)&Kt[cur][(k2 + lr) * KTP2 + ks * 32 + lh * 8];
                const bf16x8 bb = *(const bf16x8*)&Dbt[lr * DBP + ks * 32 + lh * 8];
                accS2 = __builtin_amdgcn_mfma_f32_16x16x32_bf16(a, bb, accS2, 0, 0, 0);
            }
#pragma unroll
            for (int r = 0; r < 4; ++r) accS2[r] *= bc[k2 + lh * 4 + r];
        }

        // export S -> Sbt (safe after bar1); stage next chunk into buf^1
#pragma unroll
        for (int r = 0; r < 4; ++r)
            Sbt[lr * SBP + k1 + lh * 4 + r] = f2bf(accS1[r]);
        if (k2 >= 0) {
#pragma unroll
            for (int r = 0; r < 4; ++r)
                Sbt[lr * SBP + k2 + lh * 4 + r] = f2bf(accS2[r]);
        }
        if (ch + 1 < NCH) {
            const int nxt = cur ^ 1;
#pragma unroll
            for (int i = 0; i < 3; ++i) {
                const int u = i * 256 + tid;
                const int r = u / 12, c8 = (u % 12) * 8;
                *(u16x8*)&Wn[nxt][r * WNP + c8] = wpf[i];
            }
#pragma unroll
            for (int i = 0; i < 3; ++i) {
                const int u = i * 256 + tid;
                const int c = u / 8, t8 = (u % 8) * 8;
                *(u16x8*)&Kt[nxt][c * KTP2 + t8] = kpf[i];
            }
#pragma unroll
            for (int r = 0; r < 4; ++r) ucur[r] = upf[r];
        }
        __syncthreads();   // bar2
        cur ^= 1;
    }

    // final states (f32)
    {
        float* sp = states + (size_t)bh * (HD * HD);
#pragma unroll
        for (int r = 0; r < 4; ++r)
            sp[(size_t)(k1 + lh * 4 + r) * HD + v0 + lr] = accS1[r];
        if (k2 >= 0) {
#pragma unroll
            for (int r = 0; r < 4; ++r)
                sp[(size_t)(k2 + lh * 4 + r) * HD + v0 + lr] = accS2[r];
        }
    }
}

// ---------------------------------------------------------------- KDA parallel O epilogue (MFMA)
__global__ __launch_bounds__(256)
void kda_epi(const unsigned short* __restrict__ SinT, const unsigned short* __restrict__ Qe,
             const unsigned short* __restrict__ Ol,
             const unsigned short* __restrict__ gab, const unsigned short* __restrict__ wgb,
             const float* __restrict__ onw, unsigned short* __restrict__ obf)
{
    __shared__ unsigned short Sl[96 * 104];    // S^T bf16 [v][k]
    __shared__ unsigned short Ql[64 * 104];    // Qe bf16 [t][k]
    __shared__ unsigned short Olb[64 * 104];
    __shared__ float onws[HD];

    const int bx = blockIdx.x;
    const int bh = bx >> 5, ch = bx & 31;
    const int b = bh >> 3, h = bh & 7;
    const int tid = threadIdx.x;
    const size_t cb = (size_t)b * (TT * HH * HD) + (size_t)(ch * CH) * (HH * HD) + h * HD;
    const size_t sbase = (size_t)(bh * NCH + ch) * 9216;
    const size_t tok0 = (size_t)b * TT + ch * CH;

#pragma unroll
    for (int i = 0; i < 5; ++i) {
        const int u = i * 256 + tid;
        if (u < 1152) {
            const int row = u / 12, c8 = (u % 12) * 8;
            *(u16x8*)&Sl[row * 104 + c8] = *(const u16x8*)(SinT + sbase + (size_t)row * 96 + c8);
        }
    }
#pragma unroll
    for (int i = 0; i < 3; ++i) {
        const int u = i * 256 + tid;
        const int t = u / 12, c8 = (u % 12) * 8;
        *(u16x8*)&Ql[t * 104 + c8]  = *(const u16x8*)(Qe + cb + (size_t)t * 768 + c8);
        *(u16x8*)&Olb[t * 104 + c8] = *(const u16x8*)(Ol + cb + (size_t)t * 768 + c8);
    }
    if (tid < HD) onws[tid] = onw[tid];

    const int lane = tid & 63, w = tid >> 6;
    const int lr = lane & 15, lh = lane >> 4;
    const int t0 = w * 16;

    // fused gate GEMM (global operands, L2-hot): gacc[t][v] = gab @ Wgb_h
    bf16x8 gaf[3];
#pragma unroll
    for (int ks = 0; ks < 3; ++ks)
        gaf[ks] = *(const bf16x8*)(gab + (tok0 + t0 + lr) * HD + ks * 32 + lh * 8);
    f32x4 gacc[6];
#pragma unroll
    for (int nt = 0; nt < 6; ++nt) {
        gacc[nt] = (f32x4){0.f, 0.f, 0.f, 0.f};
#pragma unroll
        for (int ks = 0; ks < 3; ++ks) {
            const bf16x8 bfr = *(const bf16x8*)(wgb +
                (size_t)(h * HD + nt * 16 + lr) * HD + ks * 32 + lh * 8);
            gacc[nt] = __builtin_amdgcn_mfma_f32_16x16x32_bf16(gaf[ks], bfr, gacc[nt], 0, 0, 0);
        }
    }
    __syncthreads();

    bf16x8 af[3];
#pragma unroll
    for (int ks = 0; ks < 3; ++ks)
        af[ks] = *(const bf16x8*)&Ql[(t0 + lr) * 104 + ks * 32 + lh * 8];

    f32x4 acc[6];
#pragma unroll
    for (int nt = 0; nt < 6; ++nt) {
#pragma unroll
        for (int r = 0; r < 4; ++r)
            acc[nt][r] = bf2f(Olb[(t0 + lh * 4 + r) * 104 + nt * 16 + lr]);
#pragma unroll
        for (int ks = 0; ks < 3; ++ks)
            acc[nt] = __builtin_amdgcn_mfma_f32_16x16x32_bf16(
                af[ks], *(const bf16x8*)&Sl[(nt * 16 + lr) * 104 + ks * 32 + lh * 8],
                acc[nt], 0, 0, 0);
    }

    float ss0 = 0.f, ss1 = 0.f, ss2 = 0.f, ss3 = 0.f;
#pragma unroll
    for (int nt = 0; nt < 6; ++nt) {
        ss0 = fmaf(acc[nt][0], acc[nt][0], ss0);
        ss1 = fmaf(acc[nt][1], acc[nt][1], ss1);
        ss2 = fmaf(acc[nt][2], acc[nt][2], ss2);
        ss3 = fmaf(acc[nt][3], acc[nt][3], ss3);
    }
#pragma unroll
    for (int d = 1; d < 16; d <<= 1) {
        ss0 += __shfl_xor(ss0, d); ss1 += __shfl_xor(ss1, d);
        ss2 += __shfl_xor(ss2, d); ss3 += __shfl_xor(ss3, d);
    }
    const float rr0 = rsqrtf(ss0 * (1.f / HD) + 1e-6f);
    const float rr1 = rsqrtf(ss1 * (1.f / HD) + 1e-6f);
    const float rr2 = rsqrtf(ss2 * (1.f / HD) + 1e-6f);
    const float rr3 = rsqrtf(ss3 * (1.f / HD) + 1e-6f);

#pragma unroll
    for (int nt = 0; nt < 6; ++nt) {
        const int v = nt * 16 + lr;
        const float ow = onws[v];
#pragma unroll
        for (int r = 0; r < 4; ++r) {
            const int t = t0 + lh * 4 + r;
            const float rrv = (r == 0) ? rr0 : (r == 1) ? rr1 : (r == 2) ? rr2 : rr3;
            const float gg = gacc[nt][r];
            const float val = acc[nt][r] * rrv * ow * (gg / (1.f + __expf(-gg)));
            obf[cb + (size_t)t * 768 + v] = f2bf(val);
        }
    }
}

// ---------------------------------------------------------------- host
extern "C" void kernel_launch(void* const* d_in, const int* in_sizes, int n_in,
                              void* d_out, int out_size, void* d_ws, size_t ws_size,
                              hipStream_t stream)
{
    (void)in_sizes; (void)n_in; (void)out_size; (void)ws_size;
    const float* hidden   = (const float*)d_in[0];
    const float* mask     = (const float*)d_in[1];
    const float* norm_a_w = (const float*)d_in[2];
    const float* norm_a_b = (const float*)d_in[3];
    const float* proj_a_w = (const float*)d_in[4];
    const float* proj_a_b = (const float*)d_in[5];
    const float* ln_w     = (const float*)d_in[6];
    const float* ln_b     = (const float*)d_in[7];
    const float* Wq       = (const float*)d_in[8];
    const float* Wk       = (const float*)d_in[9];
    const float* Wv       = (const float*)d_in[10];
    const float* Wfa      = (const float*)d_in[11];
    const float* Wfb      = (const float*)d_in[12];
    const float* dt_bias  = (const float*)d_in[13];
    const float* A_log    = (const float*)d_in[14];
    const float* Wb       = (const float*)d_in[15];
    const float* Wga      = (const float*)d_in[16];
    const float* Wgb      = (const float*)d_in[17];
    const float* onorm_w  = (const float*)d_in[18];
    const float* Wo       = (const float*)d_in[19];
    const float* Wgate    = (const float*)d_in[20];
    const float* Wup      = (const float*)d_in[21];
    const float* Wdown    = (const float*)d_in[22];

    float* ws    = (float*)d_ws;
    float* hbuf  = ws;                 // bf16 residual stream
    float* qb    = ws + HROW;          // bf16 q; dead after pre -> mg lives here
    float* kb    = ws + 2 * HROW;      // bf16 k
    float* vb    = ws + 3 * HROW;      // bf16 v -> U(bf16) -> a_bf
    float* egb   = ws + 4 * HROW;      // SinT region
    float* betab = ws + 5 * HROW;                     // MM*HH
    float* BcP   = betab + (size_t)MM * HH;           // 32*32*96
    unsigned short* SinT = (unsigned short*)egb;      // 18.9MB
    unsigned short* hb16 = (unsigned short*)hbuf;
    unsigned short* q16 = (unsigned short*)qb;
    unsigned short* k16 = (unsigned short*)kb;
    unsigned short* v16 = (unsigned short*)vb;
    unsigned short* bfp = (unsigned short*)(BcP + 32 * NCH * HD);
    unsigned short* x_bf    = bfp;  bfp += HROW;
    unsigned short* fab_bf  = bfp;  bfp += (size_t)MM * HD;
    unsigned short* gab_bf  = bfp;  bfp += (size_t)MM * HD;
    unsigned short* olb_bf  = bfp;  bfp += HROW;
    unsigned short* w_bf    = bfp;  bfp += HROW;
    unsigned short* k_bf    = bfp;  bfp += HROW;      // ktil^T [bh][ch][96][64]
    unsigned short* qe_bf   = bfp;  bfp += HROW;      // Qe bf16
    unsigned short* wt_proj = bfp;  bfp += 589824;
    unsigned short *wt_qkv[LL], *wt_o[LL], *wt_fb[LL], *wt_gb[LL],
                   *wt_gate[LL], *wt_up[LL], *wt_down[LL];
    for (int l = 0; l < LL; ++l) {
        wt_qkv[l] = bfp;  bfp += 2560 * 768;  // [q|k|v|fa|ga|beta|pad] rows
        wt_o[l] = bfp;    bfp += 589824;
        wt_fb[l] = bfp;   bfp += 73728;
        wt_gb[l] = bfp;   bfp += 73728;
        wt_gate[l] = bfp; bfp += 1572864;
        wt_up[l] = bfp;   bfp += 1572864;
        wt_down[l] = bfp; bfp += 1572864;
    }
    unsigned short* mg_bf = (unsigned short*)qb;    // q/k dead after pre
    unsigned short* a_bf  = (unsigned short*)vb;    // U dead after seq

    float* out    = (float*)d_out;
    float* states = out + HROW;

    // weight transpose+convert: ONE dispatch for everything
    transcvt_all<<<15360, 256, 0, stream>>>(proj_a_w, Wq, Wk, Wv, Wo, Wfb, Wgb,
                                            Wfa, Wga, Wb, Wgate, Wup, Wdown, wt_proj);

    layernorm_rows<<<MM, 256, 0, stream>>>(hidden, x_bf, norm_a_w, norm_a_b, nullptr);
    // h = LN(hidden)@proj + b  -> bf16 residual stream
    bgemm<BE_BIASB, 2><<<dim3(6, 64), 256, 0, stream>>>(x_bf, wt_proj, nullptr, hb16,
                                                        proj_a_b, nullptr, MM, DD, DD);

    for (int l = 0; l < LL; ++l) {
        layernorm_rows_b<<<MM, 256, 0, stream>>>(hb16, x_bf, ln_w + l * DD, ln_b + l * DD, mask);
        // fused q|k|v|fa|ga|beta in ONE GEMM (N=2560, BK=64, L2-supertiled)
        bgemm_qkvfg<<<dim3(20, 64), 256, 0, stream>>>(x_bf, wt_qkv[l], q16, k16, v16,
                                                      fab_bf, gab_bf, betab, DD);
        // chunkwise scan (EG + l2norm fused into pre; gate fused into epi)
        kda_pre<<<1024, 256, 0, stream>>>(q16, k16, v16, fab_bf, A_log + l * DD, dt_bias + l * DD,
                                          wt_fb[l], betab, olb_bf, BcP, w_bf, k_bf, qe_bf);
        kda_seq<<<192, 256, 0, stream>>>(w_bf, k_bf, v16, BcP, SinT,
                                         states + (size_t)l * BB * HH * HD * HD);
        kda_epi<<<1024, 256, 0, stream>>>(SinT, qe_bf, olb_bf, gab_bf, wt_gb[l],
                                          onorm_w + l * HD, x_bf);
        // a = o @ Wo
        bgemm<BE_BF16, 2><<<dim3(6, 64), 256, 0, stream>>>(x_bf, wt_o[l], nullptr, a_bf, nullptr, nullptr, MM, DD, DD);
        // swiglu (128x64 dual tile, BK=64, L2-supertiled)
        bgemm_dual<<<dim3(32, 64), 256, 0, stream>>>(a_bf, wt_gate[l], wt_up[l], mg_bf, MM, FF, DD);
        // h' = mg@Wdown + h : intermediate layer -> bf16 in-place; last layer -> f32 out
        if (l == LL - 1)
            bgemm<BE_RESF, 2><<<dim3(6, 64), 256, 0, stream>>>(mg_bf, wt_down[l], out, nullptr,
                                                               (const float*)hb16, nullptr, MM, DD, FF);
        else
            bgemm<BE_RESB, 2><<<dim3(6, 64), 256, 0, stream>>>(mg_bf, wt_down[l], nullptr, hb16,
                                                               (const float*)hb16, nullptr, MM, DD, FF);
    }
}